// Round 5
// baseline (6626.253 us; speedup 1.0000x reference)
//
#include <hip/hip_runtime.h>
#include <hip/hip_bf16.h>
#include <math.h>

// ---------------- conv1: x(32,3,256,256) -> z1 bf16 (32,128,128,128), k4 s2 p1, relu
__global__ __launch_bounds__(256) void conv1_relu(const float* __restrict__ x,
        const float* __restrict__ w, const float* __restrict__ bias,
        __hip_bfloat16* __restrict__ z1) {
    int gid = blockIdx.x * 256 + threadIdx.x;
    int ox = gid & 127;
    int oy = (gid >> 7) & 127;
    int ocg = (gid >> 14) & 31;
    int n = gid >> 19;
    int oc0 = ocg * 4;
    float a0 = bias[oc0], a1 = bias[oc0 + 1], a2 = bias[oc0 + 2], a3 = bias[oc0 + 3];
    int iy0 = oy * 2 - 1, ix0 = ox * 2 - 1;
    for (int c = 0; c < 3; ++c) {
        const float* xp = x + ((n * 3 + c) << 16);
        const float* wp = w + oc0 * 48 + c * 16;   // w[oc][c][ky][kx]
        for (int ky = 0; ky < 4; ++ky) {
            int iy = iy0 + ky;
            if ((unsigned)iy > 255u) continue;
            const float* xr = xp + (iy << 8);
            for (int kx = 0; kx < 4; ++kx) {
                int ix = ix0 + kx;
                if ((unsigned)ix > 255u) continue;
                float v = xr[ix];
                int wi = (ky << 2) + kx;
                a0 += v * wp[wi];
                a1 += v * wp[wi + 48];
                a2 += v * wp[wi + 96];
                a3 += v * wp[wi + 144];
            }
        }
    }
    __hip_bfloat16* zp = z1 + (((n * 128 + oc0) << 14) | (oy << 7) | ox);
    zp[0]     = __float2bfloat16(fmaxf(a0, 0.f));
    zp[16384] = __float2bfloat16(fmaxf(a1, 0.f));
    zp[32768] = __float2bfloat16(fmaxf(a2, 0.f));
    zp[49152] = __float2bfloat16(fmaxf(a3, 0.f));
}

// ---------------- repack enc_w2 (64,128,4,4) OIHW -> wt[ic*16+tap][oc]
__global__ __launch_bounds__(256) void repack_w2(const float* __restrict__ w,
                                                 float* __restrict__ wt) {
    int i = blockIdx.x * 256 + threadIdx.x;   // 131072
    int oc = i & 63;
    int tap = (i >> 6) & 15;
    int ic = i >> 10;
    wt[i] = w[(oc * 128 + ic) * 16 + tap];
}

// ---------------- conv2: z1 bf16 -> z2 NHWC f32 (32,64,64,64), k4 s2 p1
// block = (n, oy): 64 oc x 64 ox. thread: 4 oc x 4 ox. weights staged in LDS.
__global__ __launch_bounds__(256) void conv2_kernel(const __hip_bfloat16* __restrict__ z1,
        const float* __restrict__ wt, const float* __restrict__ bias,
        float* __restrict__ z2) {
    __shared__ float lw[8192];                 // 8 ic x 16 tap x 64 oc
    int bid = blockIdx.x;                      // 2048 = 32n * 64oy
    int oy = bid & 63;
    int n = bid >> 6;
    int tid = threadIdx.x;
    int oc0 = (tid & 15) * 4;
    int sp0 = tid >> 4;                        // ox = sp0 + 16*s
    float a[4][4];
    for (int s = 0; s < 4; ++s)
        for (int o = 0; o < 4; ++o) a[s][o] = bias[oc0 + o];
    int iy0 = oy * 2 - 1;
    for (int icc = 0; icc < 16; ++icc) {
        __syncthreads();
        const float4* src = (const float4*)(wt + icc * 8192);
        float4* dst = (float4*)lw;
        for (int j = 0; j < 8; ++j) dst[tid + j * 256] = src[tid + j * 256];
        __syncthreads();
        for (int ic = 0; ic < 8; ++ic) {
            const __hip_bfloat16* zp = z1 + ((n * 128 + icc * 8 + ic) << 14);
            for (int ky = 0; ky < 4; ++ky) {
                int iy = iy0 + ky;
                if ((unsigned)iy > 127u) continue;
                const __hip_bfloat16* zr = zp + (iy << 7);
                for (int kx = 0; kx < 4; ++kx) {
                    const float4 w4 = *(const float4*)(lw + (((ic << 4) + (ky << 2) + kx) << 6) + oc0);
                    for (int s = 0; s < 4; ++s) {
                        int ix = ((sp0 + (s << 4)) << 1) - 1 + kx;
                        float v = ((unsigned)ix > 127u) ? 0.f : __bfloat162float(zr[ix]);
                        a[s][0] += v * w4.x;
                        a[s][1] += v * w4.y;
                        a[s][2] += v * w4.z;
                        a[s][3] += v * w4.w;
                    }
                }
            }
        }
    }
    for (int s = 0; s < 4; ++s) {
        int ox = sp0 + (s << 4);
        float4* op = (float4*)(z2 + ((((n << 6) | oy) << 6 | ox) << 6) + oc0);
        float4 r; r.x = a[s][0]; r.y = a[s][1]; r.z = a[s][2]; r.w = a[s][3];
        *op = r;
    }
}

// ---------------- codebook norms
__global__ __launch_bounds__(256) void cb_norms(const float* __restrict__ cb,
                                                float* __restrict__ cbn) {
    int k = blockIdx.x * 256 + threadIdx.x;    // 512
    const float* cp = cb + (k << 6);
    float s = 0.f;
    for (int d = 0; d < 64; ++d) s += cp[d] * cp[d];
    cbn[k] = s;
}

// ---------------- VQ: argmin over 512 codes, loss accum, write q in place (NHWC)
__global__ __launch_bounds__(256) void vq_kernel(float* __restrict__ z2,
        const float* __restrict__ cb, const float* __restrict__ cbn,
        float* __restrict__ acc) {
    int row = blockIdx.x * 256 + threadIdx.x;  // 131072
    float4 z[16];
    const float4* zp = (const float4*)(z2 + (row << 6));
    for (int j = 0; j < 16; ++j) z[j] = zp[j];
    float best = -1e30f;
    int bi = 0;
    for (int k = 0; k < 512; ++k) {
        const float4* cp = (const float4*)(cb + (k << 6));
        float s = -0.5f * cbn[k];
        for (int j = 0; j < 16; ++j) {
            float4 c = cp[j];
            s += z[j].x * c.x + z[j].y * c.y + z[j].z * c.z + z[j].w * c.w;
        }
        if (s > best) { best = s; bi = k; }
    }
    const float4* cp = (const float4*)(cb + (bi << 6));
    float4* qp = (float4*)(z2 + (row << 6));
    float l = 0.f;
    for (int j = 0; j < 16; ++j) {
        float4 c = cp[j];
        float dx = c.x - z[j].x, dy = c.y - z[j].y;
        float dz = c.z - z[j].z, dw = c.w - z[j].w;
        l += dx * dx + dy * dy + dz * dz + dw * dw;
        qp[j] = c;
    }
    for (int off = 32; off; off >>= 1) l += __shfl_down(l, off);
    if ((threadIdx.x & 63) == 0) atomicAdd(acc, l);
}

// ---------------- deconv1: q NHWC f32 -> h bf16 (32,128,128,128), k4 s2 p1, relu
__global__ __launch_bounds__(256) void deconv1_relu(const float* __restrict__ q,
        const float* __restrict__ w,   // (ic=64, oc=128, 4, 4)
        const float* __restrict__ bias, __hip_bfloat16* __restrict__ h) {
    int bid = blockIdx.x;                      // 65536 = 32n * 32ocg * 64oyb
    int oyb = bid & 63;
    int ocg = (bid >> 6) & 31;
    int n = bid >> 11;
    int ox = threadIdx.x & 127;
    int oy = oyb * 2 + (threadIdx.x >> 7);
    int oc0 = ocg * 4;
    float a[4] = {bias[oc0], bias[oc0 + 1], bias[oc0 + 2], bias[oc0 + 3]};
    int py = (oy + 1) & 1, px = (ox + 1) & 1;
    for (int dy = 0; dy < 2; ++dy) {
        int ky = py + 2 * dy;
        int iy = (oy + 1 - ky) >> 1;
        if ((unsigned)iy > 63u) continue;
        for (int dx = 0; dx < 2; ++dx) {
            int kx = px + 2 * dx;
            int ix = (ox + 1 - kx) >> 1;
            if ((unsigned)ix > 63u) continue;
            const float4* qp = (const float4*)(q + ((((n << 6) | iy) << 6 | ix) << 6));
            const float* wp = w + oc0 * 16 + (ky << 2) + kx;
            for (int ic4 = 0; ic4 < 16; ++ic4) {
                float4 v = qp[ic4];
                const float* wq = wp + ic4 * 8192;   // 4 ic * 2048
                a[0] += v.x * wq[0];    a[1] += v.x * wq[16];
                a[2] += v.x * wq[32];   a[3] += v.x * wq[48];
                a[0] += v.y * wq[2048]; a[1] += v.y * wq[2064];
                a[2] += v.y * wq[2080]; a[3] += v.y * wq[2096];
                a[0] += v.z * wq[4096]; a[1] += v.z * wq[4112];
                a[2] += v.z * wq[4128]; a[3] += v.z * wq[4144];
                a[0] += v.w * wq[6144]; a[1] += v.w * wq[6160];
                a[2] += v.w * wq[6176]; a[3] += v.w * wq[6192];
            }
        }
    }
    __hip_bfloat16* hp = h + (((n * 128 + oc0) << 14) | (oy << 7) | ox);
    hp[0]     = __float2bfloat16(fmaxf(a[0], 0.f));
    hp[16384] = __float2bfloat16(fmaxf(a[1], 0.f));
    hp[32768] = __float2bfloat16(fmaxf(a[2], 0.f));
    hp[49152] = __float2bfloat16(fmaxf(a[3], 0.f));
}

// ---------------- deconv2: h bf16 -> recon (32,3,256,256), tanh; + loss finalize
__global__ __launch_bounds__(256) void deconv2_tanh(const __hip_bfloat16* __restrict__ h,
        const float* __restrict__ w,   // (ic=128, oc=3, 4, 4)
        const float* __restrict__ bias, const float* __restrict__ acc,
        float* __restrict__ out) {
    int gid = blockIdx.x * 256 + threadIdx.x;  // 6291456
    int ox = gid & 255;
    int oy = (gid >> 8) & 255;
    int t = gid >> 16;
    int oc = t % 3;
    int n = t / 3;
    float a = bias[oc];
    int py = (oy + 1) & 1, px = (ox + 1) & 1;
    for (int dy = 0; dy < 2; ++dy) {
        int ky = py + 2 * dy;
        int iy = (oy + 1 - ky) >> 1;
        if ((unsigned)iy > 127u) continue;
        for (int dx = 0; dx < 2; ++dx) {
            int kx = px + 2 * dx;
            int ix = (ox + 1 - kx) >> 1;
            if ((unsigned)ix > 127u) continue;
            const __hip_bfloat16* hp = h + ((n * 128) << 14) + (iy << 7) + ix;
            const float* wp = w + oc * 16 + (ky << 2) + kx;
            for (int ic = 0; ic < 128; ++ic)
                a += __bfloat162float(hp[ic << 14]) * wp[ic * 48];
        }
    }
    out[gid] = tanhf(a);
    if (gid == 0) out[6291456] = 1.25f * acc[0] / 8388608.0f;
}

extern "C" void kernel_launch(void* const* d_in, const int* in_sizes, int n_in,
                              void* d_out, int out_size, void* d_ws, size_t ws_size,
                              hipStream_t stream) {
    const float* x      = (const float*)d_in[0];
    const float* enc_w1 = (const float*)d_in[1];
    const float* enc_b1 = (const float*)d_in[2];
    const float* enc_w2 = (const float*)d_in[3];
    const float* enc_b2 = (const float*)d_in[4];
    const float* cb     = (const float*)d_in[5];
    const float* dec_w1 = (const float*)d_in[6];
    const float* dec_b1 = (const float*)d_in[7];
    const float* dec_w2 = (const float*)d_in[8];
    const float* dec_b2 = (const float*)d_in[9];
    float* out = (float*)d_out;

    // workspace layout (bytes): total ~168.3 MB
    char* base = (char*)d_ws;
    __hip_bfloat16* z1h = (__hip_bfloat16*)base;              // 67108864 bf16 = 134217728 B (z1, reused as h)
    float* z2  = (float*)(base + 134217728);                  // 8388608 f32  =  33554432 B (becomes q in place)
    float* w2t = (float*)(base + 167772160);                  // 131072 f32   =    524288 B
    float* cbn = (float*)(base + 168296448);                  // 512 f32
    float* acc = (float*)(base + 168298496);                  // 1 f32

    hipMemsetAsync(acc, 0, 4, stream);
    repack_w2<<<512, 256, 0, stream>>>(enc_w2, w2t);
    cb_norms<<<2, 256, 0, stream>>>(cb, cbn);
    conv1_relu<<<65536, 256, 0, stream>>>(x, enc_w1, enc_b1, z1h);
    conv2_kernel<<<2048, 256, 0, stream>>>(z1h, w2t, enc_b2, z2);
    vq_kernel<<<512, 256, 0, stream>>>(z2, cb, cbn, acc);
    deconv1_relu<<<65536, 256, 0, stream>>>(z2, dec_w1, dec_b1, z1h /* = h */);
    deconv2_tanh<<<24576, 256, 0, stream>>>(z1h /* = h */, dec_w2, dec_b2, acc, out);
}

// Round 7
// 3421.370 us; speedup vs baseline: 1.9367x; 1.9367x over previous
//
#include <hip/hip_runtime.h>
#include <hip/hip_bf16.h>
#include <math.h>

typedef __bf16 bf16x8 __attribute__((ext_vector_type(8)));
typedef float f32x4 __attribute__((ext_vector_type(4)));

__device__ __forceinline__ float bflo(unsigned u){ union{unsigned x;float f;}c;c.x=u<<16;return c.f;}
__device__ __forceinline__ float bfhi(unsigned u){ union{unsigned x;float f;}c;c.x=u&0xffff0000u;return c.f;}
__device__ __forceinline__ ushort f2bf(float f){ union{__hip_bfloat16 b;ushort u;}c;c.b=__float2bfloat16(f);return c.u;}

// ---------------- conv1: x(32,3,256,256) -> z1 bf16 NCHW (32,128,128,128), k4 s2 p1, relu
__global__ __launch_bounds__(256) void conv1_relu(const float* __restrict__ x,
        const float* __restrict__ w, const float* __restrict__ bias,
        __hip_bfloat16* __restrict__ z1) {
    int gid = blockIdx.x * 256 + threadIdx.x;
    int ox = gid & 127;
    int oy = (gid >> 7) & 127;
    int ocg = (gid >> 14) & 31;
    int n = gid >> 19;
    int oc0 = ocg * 4;
    float a0 = bias[oc0], a1 = bias[oc0 + 1], a2 = bias[oc0 + 2], a3 = bias[oc0 + 3];
    int iy0 = oy * 2 - 1, ix0 = ox * 2 - 1;
    for (int c = 0; c < 3; ++c) {
        const float* xp = x + ((n * 3 + c) << 16);
        const float* wp = w + oc0 * 48 + c * 16;
        for (int ky = 0; ky < 4; ++ky) {
            int iy = iy0 + ky;
            if ((unsigned)iy > 255u) continue;
            const float* xr = xp + (iy << 8);
            for (int kx = 0; kx < 4; ++kx) {
                int ix = ix0 + kx;
                if ((unsigned)ix > 255u) continue;
                float v = xr[ix];
                int wi = (ky << 2) + kx;
                a0 += v * wp[wi];
                a1 += v * wp[wi + 48];
                a2 += v * wp[wi + 96];
                a3 += v * wp[wi + 144];
            }
        }
    }
    __hip_bfloat16* zp = z1 + (((n * 128 + oc0) << 14) | (oy << 7) | ox);
    zp[0]     = __float2bfloat16(fmaxf(a0, 0.f));
    zp[16384] = __float2bfloat16(fmaxf(a1, 0.f));
    zp[32768] = __float2bfloat16(fmaxf(a2, 0.f));
    zp[49152] = __float2bfloat16(fmaxf(a3, 0.f));
}

// ---------------- repack enc_w2 (64,128,4,4) OIHW -> wt[ic*16+tap][oc]
__global__ __launch_bounds__(256) void repack_w2(const float* __restrict__ w,
                                                 float* __restrict__ wt) {
    int i = blockIdx.x * 256 + threadIdx.x;   // 131072
    int oc = i & 63;
    int tap = (i >> 6) & 15;
    int ic = i >> 10;
    wt[i] = w[(oc * 128 + ic) * 16 + tap];
}

// ---------------- repack dec_w1 (ic=64, oc=128, 4, 4) -> wB bf16 in MFMA fragment order
// wB[cls(ry,rx)][oct][kt][p][col][j]; k = kt*32+p*8+j = dy*128+dx*64+ic; ky=(1-ry)+2dy, kx=(1-rx)+2dx
__global__ __launch_bounds__(256) void repack_wdec1(const float* __restrict__ w,
                                                    ushort* __restrict__ wB) {
    int i = blockIdx.x * 256 + threadIdx.x;   // 131072
    int j   = i & 7;
    int col = (i >> 3) & 15;
    int p   = (i >> 7) & 3;
    int kt  = (i >> 9) & 7;
    int oct = (i >> 12) & 7;
    int cls = (i >> 15) & 3;
    int k = kt * 32 + p * 8 + j;
    int dy = k >> 7, dx = (k >> 6) & 1, ic = k & 63;
    int ry = cls >> 1, rx = cls & 1;
    int ky = (1 - ry) + 2 * dy, kx = (1 - rx) + 2 * dx;
    int oc = (oct << 4) | col;
    wB[i] = f2bf(w[ic * 2048 + oc * 16 + ky * 4 + kx]);
}

// ---------------- conv2: z1 bf16 NCHW -> zq bf16 NHWC (32,64,64,64), k4 s2 p1
__global__ __launch_bounds__(256) void conv2_kernel(const __hip_bfloat16* __restrict__ z1,
        const float* __restrict__ wt, const float* __restrict__ bias,
        ushort* __restrict__ zq) {
    __shared__ float lw[8192];                 // 8 ic x 16 tap x 64 oc
    int bid = blockIdx.x;                      // 2048 = 32n * 64oy
    int oy = bid & 63;
    int n = bid >> 6;
    int tid = threadIdx.x;
    int oc0 = (tid & 15) * 4;
    int sp0 = tid >> 4;
    float a[4][4];
    for (int s = 0; s < 4; ++s)
        for (int o = 0; o < 4; ++o) a[s][o] = bias[oc0 + o];
    int iy0 = oy * 2 - 1;
    for (int icc = 0; icc < 16; ++icc) {
        __syncthreads();
        const float4* src = (const float4*)(wt + icc * 8192);
        float4* dst = (float4*)lw;
        for (int j = 0; j < 8; ++j) dst[tid + j * 256] = src[tid + j * 256];
        __syncthreads();
        for (int ic = 0; ic < 8; ++ic) {
            const __hip_bfloat16* zp = z1 + ((n * 128 + icc * 8 + ic) << 14);
            for (int ky = 0; ky < 4; ++ky) {
                int iy = iy0 + ky;
                if ((unsigned)iy > 127u) continue;
                const __hip_bfloat16* zr = zp + (iy << 7);
                for (int kx = 0; kx < 4; ++kx) {
                    const float4 w4 = *(const float4*)(lw + (((ic << 4) + (ky << 2) + kx) << 6) + oc0);
                    for (int s = 0; s < 4; ++s) {
                        int ix = ((sp0 + (s << 4)) << 1) - 1 + kx;
                        float v = ((unsigned)ix > 127u) ? 0.f : __bfloat162float(zr[ix]);
                        a[s][0] += v * w4.x;
                        a[s][1] += v * w4.y;
                        a[s][2] += v * w4.z;
                        a[s][3] += v * w4.w;
                    }
                }
            }
        }
    }
    for (int s = 0; s < 4; ++s) {
        int ox = sp0 + (s << 4);
        int pix = ((n << 6) | oy) << 6 | ox;
        uint2 o;
        o.x = (unsigned)f2bf(a[s][0]) | ((unsigned)f2bf(a[s][1]) << 16);
        o.y = (unsigned)f2bf(a[s][2]) | ((unsigned)f2bf(a[s][3]) << 16);
        *(uint2*)(zq + (pix << 6) + oc0) = o;
    }
}

// ---------------- codebook norms
__global__ __launch_bounds__(256) void cb_norms(const float* __restrict__ cb,
                                                float* __restrict__ cbn) {
    int k = blockIdx.x * 256 + threadIdx.x;    // 512
    const float* cp = cb + (k << 6);
    float s = 0.f;
    for (int d = 0; d < 64; ++d) s += cp[d] * cp[d];
    cbn[k] = s;
}

// ---------------- VQ: bf16 z rows in zq; argmin, loss accum, write q bf16 in place
__global__ __launch_bounds__(256) void vq_kernel(ushort* __restrict__ zq,
        const float* __restrict__ cb, const float* __restrict__ cbn,
        float* __restrict__ acc) {
    int row = blockIdx.x * 256 + threadIdx.x;  // 131072
    const uint4* zp = (const uint4*)(zq + (row << 6));
    float4 z[16];
    for (int c = 0; c < 8; ++c) {
        uint4 u = zp[c];
        z[2*c]   = make_float4(bflo(u.x), bfhi(u.x), bflo(u.y), bfhi(u.y));
        z[2*c+1] = make_float4(bflo(u.z), bfhi(u.z), bflo(u.w), bfhi(u.w));
    }
    float best = -1e30f;
    int bi = 0;
    for (int k = 0; k < 512; ++k) {
        const float4* cp = (const float4*)(cb + (k << 6));
        float s = -0.5f * cbn[k];
        for (int j = 0; j < 16; ++j) {
            float4 c = cp[j];
            s += z[j].x * c.x + z[j].y * c.y + z[j].z * c.z + z[j].w * c.w;
        }
        if (s > best) { best = s; bi = k; }
    }
    const float4* cp = (const float4*)(cb + (bi << 6));
    uint4* qp = (uint4*)(zq + (row << 6));
    float l = 0.f;
    for (int c = 0; c < 8; ++c) {
        float4 c0 = cp[2*c], c1 = cp[2*c+1];
        float4 z0 = z[2*c],  z1v = z[2*c+1];
        float d0 = c0.x - z0.x, d1 = c0.y - z0.y, d2 = c0.z - z0.z, d3 = c0.w - z0.w;
        float d4 = c1.x - z1v.x, d5 = c1.y - z1v.y, d6 = c1.z - z1v.z, d7 = c1.w - z1v.w;
        l += d0*d0 + d1*d1 + d2*d2 + d3*d3 + d4*d4 + d5*d5 + d6*d6 + d7*d7;
        uint4 o;
        o.x = (unsigned)f2bf(c0.x) | ((unsigned)f2bf(c0.y) << 16);
        o.y = (unsigned)f2bf(c0.z) | ((unsigned)f2bf(c0.w) << 16);
        o.z = (unsigned)f2bf(c1.x) | ((unsigned)f2bf(c1.y) << 16);
        o.w = (unsigned)f2bf(c1.z) | ((unsigned)f2bf(c1.w) << 16);
        qp[c] = o;
    }
    for (int off = 32; off; off >>= 1) l += __shfl_down(l, off);
    if ((threadIdx.x & 63) == 0) atomicAdd(acc, l);
}

// ---------------- deconv1 via MFMA: q bf16 NHWC (32,64,64,64) -> h bf16 NHWC (32,128,128,128)
// block = (n, a): 64 b-positions; 8 waves = 8 oc-tiles of 16; 4 parity classes x K=256.
__global__ __launch_bounds__(512) void deconv1_mfma(const ushort* __restrict__ q,
        const ushort* __restrict__ wB, const float* __restrict__ bias,
        ushort* __restrict__ h) {
    __shared__ __align__(16) ushort lq[12672];   // 3 slots x 66 hx x 64 ic, byte^((hx&7)<<4)
    int bid = blockIdx.x;
    int a = bid & 63, n = bid >> 6;
    int tid = threadIdx.x;
    for (int c = tid; c < 1584; c += 512) {
        int slot = c / 528;
        int rem  = c - slot * 528;
        int hx   = rem >> 3;
        int icg  = rem & 7;
        uint4 val = {0u, 0u, 0u, 0u};
        int iy = a + slot - 1;
        int ix = hx - 1;
        if (hx >= 1 && hx <= 64 && (unsigned)iy < 64u)
            val = *(const uint4*)(q + ((((n << 6) | iy) << 6 | ix) << 6) + (icg << 3));
        int byt = ((((slot * 66 + hx) << 7) + (icg << 4))) ^ ((hx & 7) << 4);
        *(uint4*)((char*)lq + byt) = val;
    }
    __syncthreads();
    int l = tid & 63;
    int oct = tid >> 6;
    int col = l & 15, p = l >> 4;
    int oc = (oct << 4) | col;
    float bl = bias[oc];
    int oybase = a << 1;
    for (int cls = 0; cls < 4; ++cls) {
        int ry = cls >> 1, rx = cls & 1;
        f32x4 acc[4];
        #pragma unroll
        for (int s = 0; s < 4; ++s) { acc[s][0]=0.f; acc[s][1]=0.f; acc[s][2]=0.f; acc[s][3]=0.f; }
        #pragma unroll
        for (int kt = 0; kt < 8; ++kt) {
            uint4 braw = *(const uint4*)(wB + (((cls << 6) | (oct << 3) | kt) << 9) + (l << 3));
            bf16x8 bfrag = __builtin_bit_cast(bf16x8, braw);
            int dy = kt >> 2, dx = (kt >> 1) & 1;
            int ic0 = (kt & 1) << 5;
            int slot = 1 + ry - dy;
            #pragma unroll
            for (int sub = 0; sub < 4; ++sub) {
                int b = (sub << 4) | col;
                int hx = b + rx - dx + 1;
                int byt = ((((slot * 66 + hx) << 7) + (ic0 << 1) + (p << 4))) ^ ((hx & 7) << 4);
                bf16x8 afrag = *(const bf16x8*)((const char*)lq + byt);
                acc[sub] = __builtin_amdgcn_mfma_f32_16x16x32_bf16(afrag, bfrag, acc[sub], 0, 0, 0);
            }
        }
        int oy = oybase | ry;
        #pragma unroll
        for (int sub = 0; sub < 4; ++sub) {
            #pragma unroll
            for (int r = 0; r < 4; ++r) {
                int b = (sub << 4) + (p << 2) + r;
                int ox = (b << 1) | rx;
                float v = fmaxf(acc[sub][r] + bl, 0.f);
                h[(((((n << 7) | oy) << 7) | ox) << 7) | oc] = f2bf(v);
            }
        }
    }
}

// ---------------- deconv2: h bf16 NHWC -> recon (32,3,256,256), tanh; + loss finalize
__global__ __launch_bounds__(256) void deconv2_tanh(const ushort* __restrict__ h,
        const float* __restrict__ w,   // (ic=128, oc=3, 4, 4)
        const float* __restrict__ bias, const float* __restrict__ acc,
        float* __restrict__ out) {
    __shared__ float lw[48 * 129];             // [tap*3+oc][ic], odd stride kills bank conflicts
    int tid = threadIdx.x;
    for (int i = tid; i < 6144; i += 256) {
        int ic = i & 127;
        int r = i >> 7;                        // 0..47
        int oc = r % 3, tap = r / 3;
        lw[r * 129 + ic] = w[(ic * 3 + oc) * 16 + tap];
    }
    __syncthreads();
    int gid = blockIdx.x * 256 + tid;          // 2097152 = 32n*256oy*256ox
    int ox = gid & 255;
    int oy = (gid >> 8) & 255;
    int n = gid >> 16;
    float a0 = bias[0], a1 = bias[1], a2 = bias[2];
    int py = (oy + 1) & 1, px = (ox + 1) & 1;
    for (int dy = 0; dy < 2; ++dy) {
        int ky = py + 2 * dy;
        int iy = (oy + 1 - ky) >> 1;
        for (int dx = 0; dx < 2; ++dx) {
            int kx = px + 2 * dx;
            int ix = (ox + 1 - kx) >> 1;
            if ((unsigned)iy > 127u || (unsigned)ix > 127u) continue;
            const uint4* hp = (const uint4*)(h + ((((n << 7) | iy) << 7 | ix) << 7));
            const float* wr = lw + ((ky * 4 + kx) * 3) * 129;
            for (int c8 = 0; c8 < 16; ++c8) {
                uint4 u = hp[c8];
                float f0 = bflo(u.x), f1 = bfhi(u.x), f2 = bflo(u.y), f3 = bfhi(u.y);
                float f4 = bflo(u.z), f5 = bfhi(u.z), f6 = bflo(u.w), f7 = bfhi(u.w);
                const float* w0 = wr + c8 * 8;
                a0 += f0*w0[0] + f1*w0[1] + f2*w0[2] + f3*w0[3] + f4*w0[4] + f5*w0[5] + f6*w0[6] + f7*w0[7];
                const float* w1 = w0 + 129;
                a1 += f0*w1[0] + f1*w1[1] + f2*w1[2] + f3*w1[3] + f4*w1[4] + f5*w1[5] + f6*w1[6] + f7*w1[7];
                const float* w2 = w0 + 258;
                a2 += f0*w2[0] + f1*w2[1] + f2*w2[2] + f3*w2[3] + f4*w2[4] + f5*w2[5] + f6*w2[6] + f7*w2[7];
            }
        }
    }
    int ob = (n * 3 << 16) + (oy << 8) + ox;
    out[ob]           = tanhf(a0);
    out[ob + 65536]   = tanhf(a1);
    out[ob + 131072]  = tanhf(a2);
    if (gid == 0) out[6291456] = 1.25f * acc[0] / 8388608.0f;
}

extern "C" void kernel_launch(void* const* d_in, const int* in_sizes, int n_in,
                              void* d_out, int out_size, void* d_ws, size_t ws_size,
                              hipStream_t stream) {
    const float* x      = (const float*)d_in[0];
    const float* enc_w1 = (const float*)d_in[1];
    const float* enc_b1 = (const float*)d_in[2];
    const float* enc_w2 = (const float*)d_in[3];
    const float* enc_b2 = (const float*)d_in[4];
    const float* cb     = (const float*)d_in[5];
    const float* dec_w1 = (const float*)d_in[6];
    const float* dec_b1 = (const float*)d_in[7];
    const float* dec_w2 = (const float*)d_in[8];
    const float* dec_b2 = (const float*)d_in[9];
    float* out = (float*)d_out;

    // workspace layout (bytes): total ~151.8 MB
    char* base = (char*)d_ws;
    ushort* z1h = (ushort*)base;                    // 134217728 B: z1 bf16 NCHW, reused as h bf16 NHWC
    ushort* zq  = (ushort*)(base + 134217728);      //  16777216 B: z2 bf16 NHWC -> q bf16 in place
    float*  w2t = (float*)(base + 150994944);       //    524288 B
    ushort* wB  = (ushort*)(base + 151519232);      //    262144 B
    float*  cbn = (float*)(base + 151781376);       //      2048 B
    float*  acc = (float*)(base + 151783424);       //         4 B

    hipMemsetAsync(acc, 0, 4, stream);
    repack_w2<<<512, 256, 0, stream>>>(enc_w2, w2t);
    repack_wdec1<<<512, 256, 0, stream>>>(dec_w1, wB);
    cb_norms<<<2, 256, 0, stream>>>(cb, cbn);
    conv1_relu<<<65536, 256, 0, stream>>>(x, enc_w1, enc_b1, (__hip_bfloat16*)z1h);
    conv2_kernel<<<2048, 256, 0, stream>>>((const __hip_bfloat16*)z1h, w2t, enc_b2, zq);
    vq_kernel<<<512, 256, 0, stream>>>(zq, cb, cbn, acc);
    deconv1_mfma<<<2048, 512, 0, stream>>>(zq, wB, dec_b1, z1h);
    deconv2_tanh<<<8192, 256, 0, stream>>>(z1h, dec_w2, dec_b2, acc, out);
}

// Round 9
// 1553.482 us; speedup vs baseline: 4.2654x; 2.2024x over previous
//
#include <hip/hip_runtime.h>
#include <hip/hip_bf16.h>
#include <math.h>

typedef __bf16 bf16x8 __attribute__((ext_vector_type(8)));
typedef float f32x4 __attribute__((ext_vector_type(4)));

__device__ __forceinline__ float bflo(unsigned u){ union{unsigned x;float f;}c;c.x=u<<16;return c.f;}
__device__ __forceinline__ float bfhi(unsigned u){ union{unsigned x;float f;}c;c.x=u&0xffff0000u;return c.f;}
__device__ __forceinline__ ushort f2bf(float f){ union{__hip_bfloat16 b;ushort u;}c;c.b=__float2bfloat16(f);return c.u;}

// ---------------- repack enc_w1 (128,3,4,4) OIHW -> wt1[c*16+ky*4+kx][oc=128] f32
__global__ __launch_bounds__(256) void repack_w1(const float* __restrict__ w,
                                                 float* __restrict__ wt1) {
    int i = blockIdx.x * 256 + threadIdx.x;   // 6144
    if (i >= 6144) return;
    int oc = i & 127;
    int t = i >> 7;                           // 0..47
    wt1[i] = w[oc * 48 + t];
}

// ---------------- conv1: x(32,3,256,256) -> z1 bf16 NHWC (32,128,128,128ch), k4 s2 p1, relu
// ocg fastest: half-wave shares one pixel (x broadcast), writes coalesced uint2.
__global__ __launch_bounds__(256) void conv1_relu(const float* __restrict__ x,
        const float* __restrict__ wt1, const float* __restrict__ bias,
        ushort* __restrict__ z1) {
    int gid = blockIdx.x * 256 + threadIdx.x;
    int ocg = gid & 31;
    int ox = (gid >> 5) & 127;
    int oy = (gid >> 12) & 127;
    int n = gid >> 19;
    int oc0 = ocg * 4;
    float4 b4 = *(const float4*)(bias + oc0);
    float a0 = b4.x, a1 = b4.y, a2 = b4.z, a3 = b4.w;
    int iy0 = oy * 2 - 1, ix0 = ox * 2 - 1;
    for (int c = 0; c < 3; ++c) {
        const float* xp = x + ((n * 3 + c) << 16);
        for (int ky = 0; ky < 4; ++ky) {
            int iy = iy0 + ky;
            if ((unsigned)iy > 255u) continue;
            const float* xr = xp + (iy << 8);
            for (int kx = 0; kx < 4; ++kx) {
                int ix = ix0 + kx;
                if ((unsigned)ix > 255u) continue;
                float v = xr[ix];
                const float4 w4 = *(const float4*)(wt1 + ((c * 16 + ky * 4 + kx) << 7) + oc0);
                a0 += v * w4.x; a1 += v * w4.y; a2 += v * w4.z; a3 += v * w4.w;
            }
        }
    }
    uint2 o;
    o.x = (unsigned)f2bf(fmaxf(a0, 0.f)) | ((unsigned)f2bf(fmaxf(a1, 0.f)) << 16);
    o.y = (unsigned)f2bf(fmaxf(a2, 0.f)) | ((unsigned)f2bf(fmaxf(a3, 0.f)) << 16);
    *(uint2*)(z1 + ((((n << 7) | oy) << 7 | ox) << 7) + oc0) = o;
}

// ---------------- repack enc_w2 (64,128,4,4) OIHW -> wB2 bf16 MFMA-B fragment order
// wB2[c][t][oct][lane][j]: oc = oct*16+(l&15), ic = c*32+(l>>4)*8+j, tap t=ky*4+kx
__global__ __launch_bounds__(256) void repack_w2(const float* __restrict__ w,
                                                 ushort* __restrict__ wB2) {
    int i = blockIdx.x * 256 + threadIdx.x;   // 131072
    int j = i & 7;
    int l = (i >> 3) & 63;
    int oct = (i >> 9) & 3;
    int t = (i >> 11) & 15;
    int c = i >> 15;
    int oc = (oct << 4) | (l & 15);
    int ic = (c << 5) | ((l >> 4) << 3) | j;
    wB2[i] = f2bf(w[(oc << 11) | (ic << 4) | t]);   // oc*2048 + ic*16 + t
}

// ---------------- repack dec_w1 (ic=64, oc=128, 4, 4) -> wB bf16 in MFMA fragment order
__global__ __launch_bounds__(256) void repack_wdec1(const float* __restrict__ w,
                                                    ushort* __restrict__ wB) {
    int i = blockIdx.x * 256 + threadIdx.x;   // 131072
    int j   = i & 7;
    int col = (i >> 3) & 15;
    int p   = (i >> 7) & 3;
    int kt  = (i >> 9) & 7;
    int oct = (i >> 12) & 7;
    int cls = (i >> 15) & 3;
    int k = kt * 32 + p * 8 + j;
    int dy = k >> 7, dx = (k >> 6) & 1, ic = k & 63;
    int ry = cls >> 1, rx = cls & 1;
    int ky = (1 - ry) + 2 * dy, kx = (1 - rx) + 2 * dx;
    int oc = (oct << 4) | col;
    wB[i] = f2bf(w[ic * 2048 + oc * 16 + ky * 4 + kx]);
}

// ---------------- conv2 via MFMA: z1 bf16 NHWC -> zq bf16 NHWC (32,64,64,64), k4 s2 p1
// block = (n, oy): 64 px x 64 oc; 8 waves = 4 oc-tiles x 2 pix-halves; K = 4 ic-chunks x 16 taps x 32.
__global__ __launch_bounds__(512) void conv2_mfma(const ushort* __restrict__ z1,
        const ushort* __restrict__ wB2, const float* __restrict__ bias,
        ushort* __restrict__ zq) {
    __shared__ __align__(16) ushort lz[16896];     // 4 ky x 132 hx x 32 ic, byte^((hx&14)<<3)
    int bid = blockIdx.x;                          // 2048 = 32n * 64oy
    int oy = bid & 63, n = bid >> 6;
    int tid = threadIdx.x;
    int l = tid & 63, wid = tid >> 6;
    int oct = wid & 3, ph = wid >> 2;
    int col = l & 15, p = l >> 4;
    int iy0 = (oy << 1) - 1;
    f32x4 acc[2];
    for (int s = 0; s < 2; ++s) { acc[s][0]=0.f; acc[s][1]=0.f; acc[s][2]=0.f; acc[s][3]=0.f; }
    for (int c = 0; c < 4; ++c) {
        __syncthreads();
        for (int u = tid; u < 2080; u += 512) {
            int icg = u & 3;
            int v5 = u >> 2;                       // 0..519
            int hx = v5 % 130, ky = v5 / 130;
            int iy = iy0 + ky, ix = hx - 1;
            uint4 val = {0u, 0u, 0u, 0u};
            if ((unsigned)iy < 128u && (unsigned)ix < 128u)
                val = *(const uint4*)(z1 + ((((n << 7) | iy) << 7 | ix) << 7) + (c << 5) + (icg << 3));
            int byt = (((ky * 132 + hx) << 6) + (icg << 4)) ^ ((hx & 14) << 3);
            *(uint4*)((char*)lz + byt) = val;
        }
        __syncthreads();
        uint4 braw[16];
        const uint4* wp = (const uint4*)(wB2 + ((((c << 4) * 4) + oct) * 64 + l) * 8);
        #pragma unroll
        for (int t = 0; t < 16; ++t) braw[t] = wp[t * 256];   // stride 4*64*8 shorts = 256 uint4
        #pragma unroll
        for (int s = 0; s < 2; ++s) {
            int oxbase = ((ph << 1) | s) << 4;
            #pragma unroll
            for (int ky = 0; ky < 4; ++ky) {
                #pragma unroll
                for (int kx = 0; kx < 4; ++kx) {
                    int hx = ((oxbase + col) << 1) + kx;
                    int byt = (((ky * 132 + hx) << 6) + (p << 4)) ^ ((hx & 14) << 3);
                    bf16x8 afrag = *(const bf16x8*)((const char*)lz + byt);
                    acc[s] = __builtin_amdgcn_mfma_f32_16x16x32_bf16(afrag,
                              __builtin_bit_cast(bf16x8, braw[(ky << 2) | kx]), acc[s], 0, 0, 0);
                }
            }
        }
    }
    int oc = (oct << 4) | col;
    float bl = bias[oc];
    #pragma unroll
    for (int s = 0; s < 2; ++s) {
        int oxbase = ((ph << 1) | s) << 4;
        #pragma unroll
        for (int r = 0; r < 4; ++r) {
            int ox = oxbase + (p << 2) + r;
            zq[(((((n << 6) | oy) << 6) | ox) << 6) + oc] = f2bf(acc[s][r] + bl);
        }
    }
}

// ---------------- codebook norms
__global__ __launch_bounds__(256) void cb_norms(const float* __restrict__ cb,
                                                float* __restrict__ cbn) {
    int k = blockIdx.x * 256 + threadIdx.x;    // 512
    const float* cp = cb + (k << 6);
    float s = 0.f;
    for (int d = 0; d < 64; ++d) s += cp[d] * cp[d];
    cbn[k] = s;
}

// ---------------- VQ: bf16 z rows in zq; argmin, loss accum, write q bf16 in place
__global__ __launch_bounds__(256) void vq_kernel(ushort* __restrict__ zq,
        const float* __restrict__ cb, const float* __restrict__ cbn,
        float* __restrict__ acc) {
    int row = blockIdx.x * 256 + threadIdx.x;  // 131072
    const uint4* zp = (const uint4*)(zq + (row << 6));
    float4 z[16];
    for (int c = 0; c < 8; ++c) {
        uint4 u = zp[c];
        z[2*c]   = make_float4(bflo(u.x), bfhi(u.x), bflo(u.y), bfhi(u.y));
        z[2*c+1] = make_float4(bflo(u.z), bfhi(u.z), bflo(u.w), bfhi(u.w));
    }
    float best = -1e30f;
    int bi = 0;
    for (int k = 0; k < 512; ++k) {
        const float4* cp = (const float4*)(cb + (k << 6));
        float s = -0.5f * cbn[k];
        for (int j = 0; j < 16; ++j) {
            float4 c = cp[j];
            s += z[j].x * c.x + z[j].y * c.y + z[j].z * c.z + z[j].w * c.w;
        }
        if (s > best) { best = s; bi = k; }
    }
    const float4* cp = (const float4*)(cb + (bi << 6));
    uint4* qp = (uint4*)(zq + (row << 6));
    float l = 0.f;
    for (int c = 0; c < 8; ++c) {
        float4 c0 = cp[2*c], c1 = cp[2*c+1];
        float4 z0 = z[2*c],  z1v = z[2*c+1];
        float d0 = c0.x - z0.x, d1 = c0.y - z0.y, d2 = c0.z - z0.z, d3 = c0.w - z0.w;
        float d4 = c1.x - z1v.x, d5 = c1.y - z1v.y, d6 = c1.z - z1v.z, d7 = c1.w - z1v.w;
        l += d0*d0 + d1*d1 + d2*d2 + d3*d3 + d4*d4 + d5*d5 + d6*d6 + d7*d7;
        uint4 o;
        o.x = (unsigned)f2bf(c0.x) | ((unsigned)f2bf(c0.y) << 16);
        o.y = (unsigned)f2bf(c0.z) | ((unsigned)f2bf(c0.w) << 16);
        o.z = (unsigned)f2bf(c1.x) | ((unsigned)f2bf(c1.y) << 16);
        o.w = (unsigned)f2bf(c1.z) | ((unsigned)f2bf(c1.w) << 16);
        qp[c] = o;
    }
    for (int off = 32; off; off >>= 1) l += __shfl_down(l, off);
    if ((threadIdx.x & 63) == 0) atomicAdd(acc, l);
}

// ---------------- deconv1 via MFMA: q bf16 NHWC (32,64,64,64) -> h bf16 NHWC (32,128,128,128)
__global__ __launch_bounds__(512) void deconv1_mfma(const ushort* __restrict__ q,
        const ushort* __restrict__ wB, const float* __restrict__ bias,
        ushort* __restrict__ h) {
    __shared__ __align__(16) ushort lq[12672];   // 3 slots x 66 hx x 64 ic, byte^((hx&7)<<4)
    int bid = blockIdx.x;
    int a = bid & 63, n = bid >> 6;
    int tid = threadIdx.x;
    for (int c = tid; c < 1584; c += 512) {
        int slot = c / 528;
        int rem  = c - slot * 528;
        int hx   = rem >> 3;
        int icg  = rem & 7;
        uint4 val = {0u, 0u, 0u, 0u};
        int iy = a + slot - 1;
        int ix = hx - 1;
        if (hx >= 1 && hx <= 64 && (unsigned)iy < 64u)
            val = *(const uint4*)(q + ((((n << 6) | iy) << 6 | ix) << 6) + (icg << 3));
        int byt = ((((slot * 66 + hx) << 7) + (icg << 4))) ^ ((hx & 7) << 4);
        *(uint4*)((char*)lq + byt) = val;
    }
    __syncthreads();
    int l = tid & 63;
    int oct = tid >> 6;
    int col = l & 15, p = l >> 4;
    int oc = (oct << 4) | col;
    float bl = bias[oc];
    int oybase = a << 1;
    for (int cls = 0; cls < 4; ++cls) {
        int ry = cls >> 1, rx = cls & 1;
        f32x4 acc[4];
        #pragma unroll
        for (int s = 0; s < 4; ++s) { acc[s][0]=0.f; acc[s][1]=0.f; acc[s][2]=0.f; acc[s][3]=0.f; }
        #pragma unroll
        for (int kt = 0; kt < 8; ++kt) {
            uint4 braw = *(const uint4*)(wB + (((cls << 6) | (oct << 3) | kt) << 9) + (l << 3));
            bf16x8 bfrag = __builtin_bit_cast(bf16x8, braw);
            int dy = kt >> 2, dx = (kt >> 1) & 1;
            int ic0 = (kt & 1) << 5;
            int slot = 1 + ry - dy;
            #pragma unroll
            for (int sub = 0; sub < 4; ++sub) {
                int b = (sub << 4) | col;
                int hx = b + rx - dx + 1;
                int byt = ((((slot * 66 + hx) << 7) + (ic0 << 1) + (p << 4))) ^ ((hx & 7) << 4);
                bf16x8 afrag = *(const bf16x8*)((const char*)lq + byt);
                acc[sub] = __builtin_amdgcn_mfma_f32_16x16x32_bf16(afrag, bfrag, acc[sub], 0, 0, 0);
            }
        }
        int oy = oybase | ry;
        #pragma unroll
        for (int sub = 0; sub < 4; ++sub) {
            #pragma unroll
            for (int r = 0; r < 4; ++r) {
                int b = (sub << 4) + (p << 2) + r;
                int ox = (b << 1) | rx;
                float v = fmaxf(acc[sub][r] + bl, 0.f);
                h[(((((n << 7) | oy) << 7) | ox) << 7) | oc] = f2bf(v);
            }
        }
    }
}

// ---------------- deconv2: h bf16 NHWC -> recon (32,3,256,256), tanh; + loss finalize
__global__ __launch_bounds__(256) void deconv2_tanh(const ushort* __restrict__ h,
        const float* __restrict__ w,   // (ic=128, oc=3, 4, 4)
        const float* __restrict__ bias, const float* __restrict__ acc,
        float* __restrict__ out) {
    __shared__ float lw[48 * 129];             // [tap*3+oc][ic], odd stride kills bank conflicts
    int tid = threadIdx.x;
    for (int i = tid; i < 6144; i += 256) {
        int ic = i & 127;
        int r = i >> 7;                        // 0..47
        int oc = r % 3, tap = r / 3;
        lw[r * 129 + ic] = w[(ic * 3 + oc) * 16 + tap];
    }
    __syncthreads();
    int gid = blockIdx.x * 256 + tid;          // 2097152 = 32n*256oy*256ox
    int ox = gid & 255;
    int oy = (gid >> 8) & 255;
    int n = gid >> 16;
    float a0 = bias[0], a1 = bias[1], a2 = bias[2];
    int py = (oy + 1) & 1, px = (ox + 1) & 1;
    for (int dy = 0; dy < 2; ++dy) {
        int ky = py + 2 * dy;
        int iy = (oy + 1 - ky) >> 1;
        for (int dx = 0; dx < 2; ++dx) {
            int kx = px + 2 * dx;
            int ix = (ox + 1 - kx) >> 1;
            if ((unsigned)iy > 127u || (unsigned)ix > 127u) continue;
            const uint4* hp = (const uint4*)(h + ((((n << 7) | iy) << 7 | ix) << 7));
            const float* wr = lw + ((ky * 4 + kx) * 3) * 129;
            for (int c8 = 0; c8 < 16; ++c8) {
                uint4 u = hp[c8];
                float f0 = bflo(u.x), f1 = bfhi(u.x), f2 = bflo(u.y), f3 = bfhi(u.y);
                float f4 = bflo(u.z), f5 = bfhi(u.z), f6 = bflo(u.w), f7 = bfhi(u.w);
                const float* w0 = wr + c8 * 8;
                a0 += f0*w0[0] + f1*w0[1] + f2*w0[2] + f3*w0[3] + f4*w0[4] + f5*w0[5] + f6*w0[6] + f7*w0[7];
                const float* w1 = w0 + 129;
                a1 += f0*w1[0] + f1*w1[1] + f2*w1[2] + f3*w1[3] + f4*w1[4] + f5*w1[5] + f6*w1[6] + f7*w1[7];
                const float* w2 = w0 + 258;
                a2 += f0*w2[0] + f1*w2[1] + f2*w2[2] + f3*w2[3] + f4*w2[4] + f5*w2[5] + f6*w2[6] + f7*w2[7];
            }
        }
    }
    int ob = (n * 3 << 16) + (oy << 8) + ox;
    out[ob]           = tanhf(a0);
    out[ob + 65536]   = tanhf(a1);
    out[ob + 131072]  = tanhf(a2);
    if (gid == 0) out[6291456] = 1.25f * acc[0] / 8388608.0f;
}

extern "C" void kernel_launch(void* const* d_in, const int* in_sizes, int n_in,
                              void* d_out, int out_size, void* d_ws, size_t ws_size,
                              hipStream_t stream) {
    const float* x      = (const float*)d_in[0];
    const float* enc_w1 = (const float*)d_in[1];
    const float* enc_b1 = (const float*)d_in[2];
    const float* enc_w2 = (const float*)d_in[3];
    const float* enc_b2 = (const float*)d_in[4];
    const float* cb     = (const float*)d_in[5];
    const float* dec_w1 = (const float*)d_in[6];
    const float* dec_b1 = (const float*)d_in[7];
    const float* dec_w2 = (const float*)d_in[8];
    const float* dec_b2 = (const float*)d_in[9];
    float* out = (float*)d_out;

    // workspace layout (bytes): total ~151.5 MB (151.8 proven safe in R5)
    char* base = (char*)d_ws;
    ushort* z1h  = (ushort*)base;                   // 134217728 B: z1 bf16 NHWC, reused as h bf16 NHWC
    ushort* zq   = (ushort*)(base + 134217728);     //  16777216 B: z2 bf16 NHWC -> q bf16 in place
    ushort* wB2  = (ushort*)(base + 150994944);     //    262144 B: conv2 MFMA weights
    ushort* wB   = (ushort*)(base + 151257088);     //    262144 B: deconv1 MFMA weights
    float*  wt1  = (float*)(base + 151519232);      //     24576 B: conv1 weights [tap][oc]
    float*  cbn  = (float*)(base + 151543808);      //      2048 B
    float*  acc  = (float*)(base + 151545856);      //         4 B

    hipMemsetAsync(acc, 0, 4, stream);
    repack_w1<<<24, 256, 0, stream>>>(enc_w1, wt1);
    repack_w2<<<512, 256, 0, stream>>>(enc_w2, wB2);
    repack_wdec1<<<512, 256, 0, stream>>>(dec_w1, wB);
    cb_norms<<<2, 256, 0, stream>>>(cb, cbn);
    conv1_relu<<<65536, 256, 0, stream>>>(x, wt1, enc_b1, z1h);
    conv2_mfma<<<2048, 512, 0, stream>>>(z1h, wB2, enc_b2, zq);
    vq_kernel<<<512, 256, 0, stream>>>(zq, cb, cbn, acc);
    deconv1_mfma<<<2048, 512, 0, stream>>>(zq, wB, dec_b1, z1h);
    deconv2_tanh<<<8192, 256, 0, stream>>>(z1h, dec_w2, dec_b2, acc, out);
}

// Round 10
// 1061.804 us; speedup vs baseline: 6.2406x; 1.4631x over previous
//
#include <hip/hip_runtime.h>
#include <hip/hip_bf16.h>
#include <math.h>

typedef __bf16 bf16x8 __attribute__((ext_vector_type(8)));
typedef float f32x4 __attribute__((ext_vector_type(4)));

__device__ __forceinline__ float bflo(unsigned u){ union{unsigned x;float f;}c;c.x=u<<16;return c.f;}
__device__ __forceinline__ float bfhi(unsigned u){ union{unsigned x;float f;}c;c.x=u&0xffff0000u;return c.f;}
__device__ __forceinline__ ushort f2bf(float f){ union{__hip_bfloat16 b;ushort u;}c;c.b=__float2bfloat16(f);return c.u;}

// ---------------- repack enc_w1 (128,3,4,4) OIHW -> wt1[c*16+ky*4+kx][oc=128] f32
__global__ __launch_bounds__(256) void repack_w1(const float* __restrict__ w,
                                                 float* __restrict__ wt1) {
    int i = blockIdx.x * 256 + threadIdx.x;   // 6144
    if (i >= 6144) return;
    int oc = i & 127;
    int t = i >> 7;                           // 0..47
    wt1[i] = w[oc * 48 + t];
}

// ---------------- conv1: x(32,3,256,256) -> z1 bf16 NHWC (32,128,128,128ch), k4 s2 p1, relu
__global__ __launch_bounds__(256) void conv1_relu(const float* __restrict__ x,
        const float* __restrict__ wt1, const float* __restrict__ bias,
        ushort* __restrict__ z1) {
    int gid = blockIdx.x * 256 + threadIdx.x;
    int ocg = gid & 31;
    int ox = (gid >> 5) & 127;
    int oy = (gid >> 12) & 127;
    int n = gid >> 19;
    int oc0 = ocg * 4;
    float4 b4 = *(const float4*)(bias + oc0);
    float a0 = b4.x, a1 = b4.y, a2 = b4.z, a3 = b4.w;
    int iy0 = oy * 2 - 1, ix0 = ox * 2 - 1;
    for (int c = 0; c < 3; ++c) {
        const float* xp = x + ((n * 3 + c) << 16);
        for (int ky = 0; ky < 4; ++ky) {
            int iy = iy0 + ky;
            if ((unsigned)iy > 255u) continue;
            const float* xr = xp + (iy << 8);
            for (int kx = 0; kx < 4; ++kx) {
                int ix = ix0 + kx;
                if ((unsigned)ix > 255u) continue;
                float v = xr[ix];
                const float4 w4 = *(const float4*)(wt1 + ((c * 16 + ky * 4 + kx) << 7) + oc0);
                a0 += v * w4.x; a1 += v * w4.y; a2 += v * w4.z; a3 += v * w4.w;
            }
        }
    }
    uint2 o;
    o.x = (unsigned)f2bf(fmaxf(a0, 0.f)) | ((unsigned)f2bf(fmaxf(a1, 0.f)) << 16);
    o.y = (unsigned)f2bf(fmaxf(a2, 0.f)) | ((unsigned)f2bf(fmaxf(a3, 0.f)) << 16);
    *(uint2*)(z1 + ((((n << 7) | oy) << 7 | ox) << 7) + oc0) = o;
}

// ---------------- repack enc_w2 (64,128,4,4) OIHW -> wB2 bf16 MFMA-B fragment order
__global__ __launch_bounds__(256) void repack_w2(const float* __restrict__ w,
                                                 ushort* __restrict__ wB2) {
    int i = blockIdx.x * 256 + threadIdx.x;   // 131072
    int j = i & 7;
    int l = (i >> 3) & 63;
    int oct = (i >> 9) & 3;
    int t = (i >> 11) & 15;
    int c = i >> 15;
    int oc = (oct << 4) | (l & 15);
    int ic = (c << 5) | ((l >> 4) << 3) | j;
    wB2[i] = f2bf(w[(oc << 11) | (ic << 4) | t]);   // oc*2048 + ic*16 + t
}

// ---------------- repack dec_w1 (ic=64, oc=128, 4, 4) -> wB bf16 in MFMA fragment order
__global__ __launch_bounds__(256) void repack_wdec1(const float* __restrict__ w,
                                                    ushort* __restrict__ wB) {
    int i = blockIdx.x * 256 + threadIdx.x;   // 131072
    int j   = i & 7;
    int col = (i >> 3) & 15;
    int p   = (i >> 7) & 3;
    int kt  = (i >> 9) & 7;
    int oct = (i >> 12) & 7;
    int cls = (i >> 15) & 3;
    int k = kt * 32 + p * 8 + j;
    int dy = k >> 7, dx = (k >> 6) & 1, ic = k & 63;
    int ry = cls >> 1, rx = cls & 1;
    int ky = (1 - ry) + 2 * dy, kx = (1 - rx) + 2 * dx;
    int oc = (oct << 4) | col;
    wB[i] = f2bf(w[ic * 2048 + oc * 16 + ky * 4 + kx]);
}

// ---------------- repack codebook (512,64) f32 -> cbB bf16 MFMA-B fragments
// cbB[t][h][l][j]: code = t*16+(l&15), k = h*32+(l>>4)*8+j
__global__ __launch_bounds__(256) void repack_cb(const float* __restrict__ cb,
                                                 ushort* __restrict__ cbB) {
    int i = blockIdx.x * 256 + threadIdx.x;   // 32768
    int j = i & 7;
    int l = (i >> 3) & 63;
    int h = (i >> 9) & 1;
    int t = i >> 10;
    int code = (t << 4) | (l & 15);
    int k = (h << 5) | ((l >> 4) << 3) | j;
    cbB[i] = f2bf(cb[(code << 6) | k]);
}

// ---------------- conv2 via MFMA: z1 bf16 NHWC -> zq bf16 NHWC (32,64,64,64), k4 s2 p1
__global__ __launch_bounds__(512) void conv2_mfma(const ushort* __restrict__ z1,
        const ushort* __restrict__ wB2, const float* __restrict__ bias,
        ushort* __restrict__ zq) {
    __shared__ __align__(16) ushort lz[16896];     // 4 ky x 132 hx x 32 ic, byte^((hx&14)<<3)
    int bid = blockIdx.x;                          // 2048 = 32n * 64oy
    int oy = bid & 63, n = bid >> 6;
    int tid = threadIdx.x;
    int l = tid & 63, wid = tid >> 6;
    int oct = wid & 3, ph = wid >> 2;
    int col = l & 15, p = l >> 4;
    int iy0 = (oy << 1) - 1;
    f32x4 acc[2];
    for (int s = 0; s < 2; ++s) { acc[s][0]=0.f; acc[s][1]=0.f; acc[s][2]=0.f; acc[s][3]=0.f; }
    for (int c = 0; c < 4; ++c) {
        __syncthreads();
        for (int u = tid; u < 2080; u += 512) {
            int icg = u & 3;
            int v5 = u >> 2;                       // 0..519
            int hx = v5 % 130, ky = v5 / 130;
            int iy = iy0 + ky, ix = hx - 1;
            uint4 val = {0u, 0u, 0u, 0u};
            if ((unsigned)iy < 128u && (unsigned)ix < 128u)
                val = *(const uint4*)(z1 + ((((n << 7) | iy) << 7 | ix) << 7) + (c << 5) + (icg << 3));
            int byt = (((ky * 132 + hx) << 6) + (icg << 4)) ^ ((hx & 14) << 3);
            *(uint4*)((char*)lz + byt) = val;
        }
        __syncthreads();
        uint4 braw[16];
        const uint4* wp = (const uint4*)(wB2 + ((((c << 4) * 4) + oct) * 64 + l) * 8);
        #pragma unroll
        for (int t = 0; t < 16; ++t) braw[t] = wp[t * 256];   // stride 4*64*8 shorts = 256 uint4
        #pragma unroll
        for (int s = 0; s < 2; ++s) {
            int oxbase = ((ph << 1) | s) << 4;
            #pragma unroll
            for (int ky = 0; ky < 4; ++ky) {
                #pragma unroll
                for (int kx = 0; kx < 4; ++kx) {
                    int hx = ((oxbase + col) << 1) + kx;
                    int byt = (((ky * 132 + hx) << 6) + (p << 4)) ^ ((hx & 14) << 3);
                    bf16x8 afrag = *(const bf16x8*)((const char*)lz + byt);
                    acc[s] = __builtin_amdgcn_mfma_f32_16x16x32_bf16(afrag,
                              __builtin_bit_cast(bf16x8, braw[(ky << 2) | kx]), acc[s], 0, 0, 0);
                }
            }
        }
    }
    int oc = (oct << 4) | col;
    float bl = bias[oc];
    #pragma unroll
    for (int s = 0; s < 2; ++s) {
        int oxbase = ((ph << 1) | s) << 4;
        #pragma unroll
        for (int r = 0; r < 4; ++r) {
            int ox = oxbase + (p << 2) + r;
            zq[(((((n << 6) | oy) << 6) | ox) << 6) + oc] = f2bf(acc[s][r] + bl);
        }
    }
}

// ---------------- codebook norms
__global__ __launch_bounds__(256) void cb_norms(const float* __restrict__ cb,
                                                float* __restrict__ cbn) {
    int k = blockIdx.x * 256 + threadIdx.x;    // 512
    const float* cp = cb + (k << 6);
    float s = 0.f;
    for (int d = 0; d < 64; ++d) s += cp[d] * cp[d];
    cbn[k] = s;
}

// ---------------- VQ via MFMA: scores = z @ cb^T - 0.5|c|^2; argmax; loss; q in place
// block = 256 rows (4 waves x 64 rows); 32 code-tiles x K=64.
__global__ __launch_bounds__(256) void vq_mfma(ushort* __restrict__ zq,
        const float* __restrict__ cb, const float* __restrict__ cbn,
        const ushort* __restrict__ cbB, float* __restrict__ accum) {
    __shared__ int sidx[256];
    int bid = blockIdx.x;                       // 512
    int tid = threadIdx.x;
    int w = tid >> 6, l = tid & 63;
    int rowbase = (bid << 8) + (w << 6);        // wave's 64 rows
    // A-fragments: 4 row-tiles x 2 k-slices (validated mapping: row=l&15, k=(l>>4)*8+j)
    bf16x8 a0[4], a1[4];
    const ushort* zb = zq + ((size_t)rowbase << 6);
    #pragma unroll
    for (int s = 0; s < 4; ++s) {
        int r = (s << 4) | (l & 15);
        a0[s] = *(const bf16x8*)(zb + (r << 6) + ((l >> 4) << 3));
        a1[s] = *(const bf16x8*)(zb + (r << 6) + 32 + ((l >> 4) << 3));
    }
    float best[4][4];
    int bidx[4][4];
    #pragma unroll
    for (int s = 0; s < 4; ++s)
        for (int r = 0; r < 4; ++r) { best[s][r] = -1e30f; bidx[s][r] = 0; }
    for (int t = 0; t < 32; ++t) {
        int code = (t << 4) | (l & 15);
        float init = -0.5f * cbn[code];
        uint4 b0r = *(const uint4*)(cbB + (t << 10) + (l << 3));
        uint4 b1r = *(const uint4*)(cbB + (t << 10) + 512 + (l << 3));
        bf16x8 b0 = __builtin_bit_cast(bf16x8, b0r);
        bf16x8 b1 = __builtin_bit_cast(bf16x8, b1r);
        #pragma unroll
        for (int s = 0; s < 4; ++s) {
            f32x4 acc;
            acc[0] = init; acc[1] = init; acc[2] = init; acc[3] = init;
            acc = __builtin_amdgcn_mfma_f32_16x16x32_bf16(a0[s], b0, acc, 0, 0, 0);
            acc = __builtin_amdgcn_mfma_f32_16x16x32_bf16(a1[s], b1, acc, 0, 0, 0);
            #pragma unroll
            for (int r = 0; r < 4; ++r) {
                if (acc[r] > best[s][r]) { best[s][r] = acc[r]; bidx[s][r] = code; }
            }
        }
    }
    // butterfly over the 16 col-lanes: (score desc, idx asc)
    #pragma unroll
    for (int m = 1; m < 16; m <<= 1) {
        #pragma unroll
        for (int s = 0; s < 4; ++s)
            #pragma unroll
            for (int r = 0; r < 4; ++r) {
                float ob = __shfl_xor(best[s][r], m, 64);
                int oi = __shfl_xor(bidx[s][r], m, 64);
                if (ob > best[s][r] || (ob == best[s][r] && oi < bidx[s][r])) {
                    best[s][r] = ob; bidx[s][r] = oi;
                }
            }
    }
    if ((l & 15) == 0) {
        #pragma unroll
        for (int s = 0; s < 4; ++s)
            #pragma unroll
            for (int r = 0; r < 4; ++r)
                sidx[(w << 6) | (s << 4) | ((l >> 4) << 2) | r] = bidx[s][r];
    }
    __syncthreads();
    // epilogue: 1024 tasks = 256 rows x 4 quarters; gather f32 code, loss, write q
    float lpart = 0.f;
    for (int u = tid; u < 1024; u += 256) {
        int row = u >> 2, qt = u & 3;
        int idx = sidx[row];
        size_t zoff = (((size_t)(bid << 8) + row) << 6) + (qt << 4);
        const float4* cp = (const float4*)(cb + (idx << 6) + (qt << 4));
        uint4* zp = (uint4*)(zq + zoff);
        uint4 u0 = zp[0], u1 = zp[1];
        float4 c0 = cp[0], c1 = cp[1], c2 = cp[2], c3 = cp[3];
        float d;
        d = c0.x - bflo(u0.x); lpart += d * d;
        d = c0.y - bfhi(u0.x); lpart += d * d;
        d = c0.z - bflo(u0.y); lpart += d * d;
        d = c0.w - bfhi(u0.y); lpart += d * d;
        d = c1.x - bflo(u0.z); lpart += d * d;
        d = c1.y - bfhi(u0.z); lpart += d * d;
        d = c1.z - bflo(u0.w); lpart += d * d;
        d = c1.w - bfhi(u0.w); lpart += d * d;
        d = c2.x - bflo(u1.x); lpart += d * d;
        d = c2.y - bfhi(u1.x); lpart += d * d;
        d = c2.z - bflo(u1.y); lpart += d * d;
        d = c2.w - bfhi(u1.y); lpart += d * d;
        d = c3.x - bflo(u1.z); lpart += d * d;
        d = c3.y - bfhi(u1.z); lpart += d * d;
        d = c3.z - bflo(u1.w); lpart += d * d;
        d = c3.w - bfhi(u1.w); lpart += d * d;
        uint4 o0, o1;
        o0.x = (unsigned)f2bf(c0.x) | ((unsigned)f2bf(c0.y) << 16);
        o0.y = (unsigned)f2bf(c0.z) | ((unsigned)f2bf(c0.w) << 16);
        o0.z = (unsigned)f2bf(c1.x) | ((unsigned)f2bf(c1.y) << 16);
        o0.w = (unsigned)f2bf(c1.z) | ((unsigned)f2bf(c1.w) << 16);
        o1.x = (unsigned)f2bf(c2.x) | ((unsigned)f2bf(c2.y) << 16);
        o1.y = (unsigned)f2bf(c2.z) | ((unsigned)f2bf(c2.w) << 16);
        o1.z = (unsigned)f2bf(c3.x) | ((unsigned)f2bf(c3.y) << 16);
        o1.w = (unsigned)f2bf(c3.z) | ((unsigned)f2bf(c3.w) << 16);
        zp[0] = o0; zp[1] = o1;
    }
    for (int off = 32; off; off >>= 1) lpart += __shfl_down(lpart, off);
    if ((tid & 63) == 0) atomicAdd(accum, lpart);
}

// ---------------- deconv1 via MFMA: q bf16 NHWC (32,64,64,64) -> h bf16 NHWC (32,128,128,128)
__global__ __launch_bounds__(512) void deconv1_mfma(const ushort* __restrict__ q,
        const ushort* __restrict__ wB, const float* __restrict__ bias,
        ushort* __restrict__ h) {
    __shared__ __align__(16) ushort lq[12672];   // 3 slots x 66 hx x 64 ic, byte^((hx&7)<<4)
    int bid = blockIdx.x;
    int a = bid & 63, n = bid >> 6;
    int tid = threadIdx.x;
    for (int c = tid; c < 1584; c += 512) {
        int slot = c / 528;
        int rem  = c - slot * 528;
        int hx   = rem >> 3;
        int icg  = rem & 7;
        uint4 val = {0u, 0u, 0u, 0u};
        int iy = a + slot - 1;
        int ix = hx - 1;
        if (hx >= 1 && hx <= 64 && (unsigned)iy < 64u)
            val = *(const uint4*)(q + ((((n << 6) | iy) << 6 | ix) << 6) + (icg << 3));
        int byt = ((((slot * 66 + hx) << 7) + (icg << 4))) ^ ((hx & 7) << 4);
        *(uint4*)((char*)lq + byt) = val;
    }
    __syncthreads();
    int l = tid & 63;
    int oct = tid >> 6;
    int col = l & 15, p = l >> 4;
    int oc = (oct << 4) | col;
    float bl = bias[oc];
    int oybase = a << 1;
    for (int cls = 0; cls < 4; ++cls) {
        int ry = cls >> 1, rx = cls & 1;
        f32x4 acc[4];
        #pragma unroll
        for (int s = 0; s < 4; ++s) { acc[s][0]=0.f; acc[s][1]=0.f; acc[s][2]=0.f; acc[s][3]=0.f; }
        #pragma unroll
        for (int kt = 0; kt < 8; ++kt) {
            uint4 braw = *(const uint4*)(wB + (((cls << 6) | (oct << 3) | kt) << 9) + (l << 3));
            bf16x8 bfrag = __builtin_bit_cast(bf16x8, braw);
            int dy = kt >> 2, dx = (kt >> 1) & 1;
            int ic0 = (kt & 1) << 5;
            int slot = 1 + ry - dy;
            #pragma unroll
            for (int sub = 0; sub < 4; ++sub) {
                int b = (sub << 4) | col;
                int hx = b + rx - dx + 1;
                int byt = ((((slot * 66 + hx) << 7) + (ic0 << 1) + (p << 4))) ^ ((hx & 7) << 4);
                bf16x8 afrag = *(const bf16x8*)((const char*)lq + byt);
                acc[sub] = __builtin_amdgcn_mfma_f32_16x16x32_bf16(afrag, bfrag, acc[sub], 0, 0, 0);
            }
        }
        int oy = oybase | ry;
        #pragma unroll
        for (int sub = 0; sub < 4; ++sub) {
            #pragma unroll
            for (int r = 0; r < 4; ++r) {
                int b = (sub << 4) + (p << 2) + r;
                int ox = (b << 1) | rx;
                float v = fmaxf(acc[sub][r] + bl, 0.f);
                h[(((((n << 7) | oy) << 7) | ox) << 7) | oc] = f2bf(v);
            }
        }
    }
}

// ---------------- deconv2: h bf16 NHWC -> recon (32,3,256,256), tanh; + loss finalize
__global__ __launch_bounds__(256) void deconv2_tanh(const ushort* __restrict__ h,
        const float* __restrict__ w,   // (ic=128, oc=3, 4, 4)
        const float* __restrict__ bias, const float* __restrict__ acc,
        float* __restrict__ out) {
    __shared__ float lw[48 * 129];             // [tap*3+oc][ic], odd stride kills bank conflicts
    int tid = threadIdx.x;
    for (int i = tid; i < 6144; i += 256) {
        int ic = i & 127;
        int r = i >> 7;                        // 0..47
        int oc = r % 3, tap = r / 3;
        lw[r * 129 + ic] = w[(ic * 3 + oc) * 16 + tap];
    }
    __syncthreads();
    int gid = blockIdx.x * 256 + tid;          // 2097152 = 32n*256oy*256ox
    int ox = gid & 255;
    int oy = (gid >> 8) & 255;
    int n = gid >> 16;
    float a0 = bias[0], a1 = bias[1], a2 = bias[2];
    int py = (oy + 1) & 1, px = (ox + 1) & 1;
    for (int dy = 0; dy < 2; ++dy) {
        int ky = py + 2 * dy;
        int iy = (oy + 1 - ky) >> 1;
        for (int dx = 0; dx < 2; ++dx) {
            int kx = px + 2 * dx;
            int ix = (ox + 1 - kx) >> 1;
            if ((unsigned)iy > 127u || (unsigned)ix > 127u) continue;
            const uint4* hp = (const uint4*)(h + ((((n << 7) | iy) << 7 | ix) << 7));
            const float* wr = lw + ((ky * 4 + kx) * 3) * 129;
            for (int c8 = 0; c8 < 16; ++c8) {
                uint4 u = hp[c8];
                float f0 = bflo(u.x), f1 = bfhi(u.x), f2 = bflo(u.y), f3 = bfhi(u.y);
                float f4 = bflo(u.z), f5 = bfhi(u.z), f6 = bflo(u.w), f7 = bfhi(u.w);
                const float* w0 = wr + c8 * 8;
                a0 += f0*w0[0] + f1*w0[1] + f2*w0[2] + f3*w0[3] + f4*w0[4] + f5*w0[5] + f6*w0[6] + f7*w0[7];
                const float* w1 = w0 + 129;
                a1 += f0*w1[0] + f1*w1[1] + f2*w1[2] + f3*w1[3] + f4*w1[4] + f5*w1[5] + f6*w1[6] + f7*w1[7];
                const float* w2 = w0 + 258;
                a2 += f0*w2[0] + f1*w2[1] + f2*w2[2] + f3*w2[3] + f4*w2[4] + f5*w2[5] + f6*w2[6] + f7*w2[7];
            }
        }
    }
    int ob = (n * 3 << 16) + (oy << 8) + ox;
    out[ob]           = tanhf(a0);
    out[ob + 65536]   = tanhf(a1);
    out[ob + 131072]  = tanhf(a2);
    if (gid == 0) out[6291456] = 1.25f * acc[0] / 8388608.0f;
}

extern "C" void kernel_launch(void* const* d_in, const int* in_sizes, int n_in,
                              void* d_out, int out_size, void* d_ws, size_t ws_size,
                              hipStream_t stream) {
    const float* x      = (const float*)d_in[0];
    const float* enc_w1 = (const float*)d_in[1];
    const float* enc_b1 = (const float*)d_in[2];
    const float* enc_w2 = (const float*)d_in[3];
    const float* enc_b2 = (const float*)d_in[4];
    const float* cb     = (const float*)d_in[5];
    const float* dec_w1 = (const float*)d_in[6];
    const float* dec_b1 = (const float*)d_in[7];
    const float* dec_w2 = (const float*)d_in[8];
    const float* dec_b2 = (const float*)d_in[9];
    float* out = (float*)d_out;

    // workspace layout (bytes): total ~151.7 MB (151.8 proven safe in R5)
    char* base = (char*)d_ws;
    ushort* z1h  = (ushort*)base;                   // 134217728 B: z1 bf16 NHWC, reused as h bf16 NHWC
    ushort* zq   = (ushort*)(base + 134217728);     //  16777216 B: z2 bf16 NHWC -> q bf16 in place
    ushort* wB2  = (ushort*)(base + 150994944);     //    262144 B: conv2 MFMA weights
    ushort* wB   = (ushort*)(base + 151257088);     //    262144 B: deconv1 MFMA weights
    float*  wt1  = (float*)(base + 151519232);      //     24576 B: conv1 weights [tap][oc]
    ushort* cbB  = (ushort*)(base + 151543808);     //     65536 B: codebook MFMA-B fragments
    float*  cbn  = (float*)(base + 151609344);      //      2048 B
    float*  acc  = (float*)(base + 151611392);      //         4 B

    hipMemsetAsync(acc, 0, 4, stream);
    repack_w1<<<24, 256, 0, stream>>>(enc_w1, wt1);
    repack_w2<<<512, 256, 0, stream>>>(enc_w2, wB2);
    repack_wdec1<<<512, 256, 0, stream>>>(dec_w1, wB);
    repack_cb<<<128, 256, 0, stream>>>(cb, cbB);
    cb_norms<<<2, 256, 0, stream>>>(cb, cbn);
    conv1_relu<<<65536, 256, 0, stream>>>(x, wt1, enc_b1, z1h);
    conv2_mfma<<<2048, 512, 0, stream>>>(z1h, wB2, enc_b2, zq);
    vq_mfma<<<512, 256, 0, stream>>>(zq, cb, cbn, cbB, acc);
    deconv1_mfma<<<2048, 512, 0, stream>>>(zq, wB, dec_b1, z1h);
    deconv2_tanh<<<8192, 256, 0, stream>>>(z1h, dec_w2, dec_b2, acc, out);
}

// Round 12
// 600.965 us; speedup vs baseline: 11.0260x; 1.7668x over previous
//
#include <hip/hip_runtime.h>
#include <hip/hip_bf16.h>
#include <math.h>

typedef __bf16 bf16x8 __attribute__((ext_vector_type(8)));
typedef float f32x4 __attribute__((ext_vector_type(4)));

__device__ __forceinline__ float bflo(unsigned u){ union{unsigned x;float f;}c;c.x=u<<16;return c.f;}
__device__ __forceinline__ float bfhi(unsigned u){ union{unsigned x;float f;}c;c.x=u&0xffff0000u;return c.f;}
__device__ __forceinline__ ushort f2bf(float f){ union{__hip_bfloat16 b;ushort u;}c;c.b=__float2bfloat16(f);return c.u;}

// ---------------- repack enc_w1 (128,3,4,4) OIHW -> wB1 bf16 MFMA-B fragments
// wB1[h][oct][l][j]: oc = oct*16+(l&15), k = h*32+(l>>4)*8+j (k>=48 -> 0); k = c*16+ky*4+kx
__global__ __launch_bounds__(256) void repack_wb1(const float* __restrict__ w,
                                                  ushort* __restrict__ wB1) {
    int i = blockIdx.x * 256 + threadIdx.x;   // 8192
    if (i >= 8192) return;
    int j = i & 7;
    int l = (i >> 3) & 63;
    int oct = (i >> 9) & 7;
    int h = i >> 12;
    int oc = (oct << 4) | (l & 15);
    int k = (h << 5) | ((l >> 4) << 3) | j;
    wB1[i] = (k < 48) ? f2bf(w[oc * 48 + k]) : (ushort)0;
}

// ---------------- conv1 via MFMA: x f32 NCHW -> z1 bf16 NHWC (32,128,128,128), k4 s2 p1, relu
// block = (n, oy): M=128 ox, N=128 oc, K=48(pad 64). im2col tile in LDS.
__global__ __launch_bounds__(512) void conv1_mfma(const float* __restrict__ x,
        const ushort* __restrict__ wB1, const float* __restrict__ bias,
        ushort* __restrict__ z1) {
    __shared__ __align__(16) ushort lx[8192];   // [row=ox][k 0..63] bf16, byte^((row&7)<<4)
    int bid = blockIdx.x;                       // 4096 = 32n * 128oy
    int oy = bid & 127, n = bid >> 7;
    int tid = threadIdx.x;
    int iy0 = (oy << 1) - 1;
    for (int u = tid; u < 1024; u += 512) {
        int row = u & 127, ch = u >> 7;         // ch = 16B chunk of k (8 bf16)
        uint4 val = {0u, 0u, 0u, 0u};
        if (ch < 6) {
            int c = ch >> 1, kyb = (ch & 1) << 1;
            int ix0 = (row << 1) - 1;
            const float* xp = x + ((n * 3 + c) << 16);
            float f[8];
            #pragma unroll
            for (int jj = 0; jj < 2; ++jj) {
                int iy = iy0 + kyb + jj;
                bool yok = (unsigned)iy < 256u;
                const float* xr = xp + (iy << 8);
                #pragma unroll
                for (int kx = 0; kx < 4; ++kx) {
                    int ix = ix0 + kx;
                    f[jj * 4 + kx] = (yok && (unsigned)ix < 256u) ? xr[ix] : 0.f;
                }
            }
            val.x = (unsigned)f2bf(f[0]) | ((unsigned)f2bf(f[1]) << 16);
            val.y = (unsigned)f2bf(f[2]) | ((unsigned)f2bf(f[3]) << 16);
            val.z = (unsigned)f2bf(f[4]) | ((unsigned)f2bf(f[5]) << 16);
            val.w = (unsigned)f2bf(f[6]) | ((unsigned)f2bf(f[7]) << 16);
        }
        int byt = ((row << 7) + (ch << 4)) ^ ((row & 7) << 4);
        *(uint4*)((char*)lx + byt) = val;
    }
    __syncthreads();
    int l = tid & 63, w = tid >> 6;
    int rowhalf = w >> 2, ocq = w & 3;          // rows 64*rowhalf.., oc-tiles 2ocq,2ocq+1
    int col = l & 15, p = l >> 4;
    bf16x8 bf[2][2];
    float bl[2];
    #pragma unroll
    for (int t = 0; t < 2; ++t) {
        int oct = (ocq << 1) | t;
        bl[t] = bias[(oct << 4) | col];
        #pragma unroll
        for (int h = 0; h < 2; ++h) {
            uint4 br = *(const uint4*)(wB1 + ((((h << 3) | oct) << 6) + l) * 8);
            bf[t][h] = __builtin_bit_cast(bf16x8, br);
        }
    }
    #pragma unroll
    for (int s = 0; s < 4; ++s) {
        int row = (rowhalf << 6) + (s << 4) + col;   // A-row = pixel
        int sw = (row & 7) << 4;
        bf16x8 a0 = *(const bf16x8*)((const char*)lx + ((row << 7) | (((0 << 2 | p) << 4) ^ sw)));
        bf16x8 a1 = *(const bf16x8*)((const char*)lx + ((row << 7) | (((1 << 2 | p) << 4) ^ sw)));
        #pragma unroll
        for (int t = 0; t < 2; ++t) {
            f32x4 acc;
            acc[0] = bl[t]; acc[1] = bl[t]; acc[2] = bl[t]; acc[3] = bl[t];
            acc = __builtin_amdgcn_mfma_f32_16x16x32_bf16(a0, bf[t][0], acc, 0, 0, 0);
            acc = __builtin_amdgcn_mfma_f32_16x16x32_bf16(a1, bf[t][1], acc, 0, 0, 0);
            int oc = ((((ocq << 1) | t) << 4)) | col;
            ushort* zp = z1 + ((((n << 7) | oy) << 7) << 7) + oc;
            #pragma unroll
            for (int r = 0; r < 4; ++r) {
                int ox = (rowhalf << 6) + (s << 4) + (p << 2) + r;
                zp[ox << 7] = f2bf(fmaxf(acc[r], 0.f));
            }
        }
    }
}

// ---------------- repack enc_w2 (64,128,4,4) OIHW -> wB2 bf16 MFMA-B fragment order
__global__ __launch_bounds__(256) void repack_w2(const float* __restrict__ w,
                                                 ushort* __restrict__ wB2) {
    int i = blockIdx.x * 256 + threadIdx.x;   // 131072
    int j = i & 7;
    int l = (i >> 3) & 63;
    int oct = (i >> 9) & 3;
    int t = (i >> 11) & 15;
    int c = i >> 15;
    int oc = (oct << 4) | (l & 15);
    int ic = (c << 5) | ((l >> 4) << 3) | j;
    wB2[i] = f2bf(w[(oc << 11) | (ic << 4) | t]);   // oc*2048 + ic*16 + t
}

// ---------------- repack dec_w1 (ic=64, oc=128, 4, 4) -> wB bf16 in MFMA fragment order
__global__ __launch_bounds__(256) void repack_wdec1(const float* __restrict__ w,
                                                    ushort* __restrict__ wB) {
    int i = blockIdx.x * 256 + threadIdx.x;   // 131072
    int j   = i & 7;
    int col = (i >> 3) & 15;
    int p   = (i >> 7) & 3;
    int kt  = (i >> 9) & 7;
    int oct = (i >> 12) & 7;
    int cls = (i >> 15) & 3;
    int k = kt * 32 + p * 8 + j;
    int dy = k >> 7, dx = (k >> 6) & 1, ic = k & 63;
    int ry = cls >> 1, rx = cls & 1;
    int ky = (1 - ry) + 2 * dy, kx = (1 - rx) + 2 * dx;
    int oc = (oct << 4) | col;
    wB[i] = f2bf(w[ic * 2048 + oc * 16 + ky * 4 + kx]);
}

// ---------------- repack codebook (512,64) f32 -> cbB bf16 MFMA-B fragments
__global__ __launch_bounds__(256) void repack_cb(const float* __restrict__ cb,
                                                 ushort* __restrict__ cbB) {
    int i = blockIdx.x * 256 + threadIdx.x;   // 32768
    int j = i & 7;
    int l = (i >> 3) & 63;
    int h = (i >> 9) & 1;
    int t = i >> 10;
    int code = (t << 4) | (l & 15);
    int k = (h << 5) | ((l >> 4) << 3) | j;
    cbB[i] = f2bf(cb[(code << 6) | k]);
}

// ---------------- conv2 via MFMA: z1 bf16 NHWC -> zq bf16 NHWC (32,64,64,64), k4 s2 p1
__global__ __launch_bounds__(512) void conv2_mfma(const ushort* __restrict__ z1,
        const ushort* __restrict__ wB2, const float* __restrict__ bias,
        ushort* __restrict__ zq) {
    __shared__ __align__(16) ushort lz[16896];     // 4 ky x 132 hx x 32 ic, byte^((hx&14)<<3)
    int bid = blockIdx.x;                          // 2048 = 32n * 64oy
    int oy = bid & 63, n = bid >> 6;
    int tid = threadIdx.x;
    int l = tid & 63, wid = tid >> 6;
    int oct = wid & 3, ph = wid >> 2;
    int col = l & 15, p = l >> 4;
    int iy0 = (oy << 1) - 1;
    f32x4 acc[2];
    for (int s = 0; s < 2; ++s) { acc[s][0]=0.f; acc[s][1]=0.f; acc[s][2]=0.f; acc[s][3]=0.f; }
    for (int c = 0; c < 4; ++c) {
        __syncthreads();
        for (int u = tid; u < 2080; u += 512) {
            int icg = u & 3;
            int v5 = u >> 2;                       // 0..519
            int hx = v5 % 130, ky = v5 / 130;
            int iy = iy0 + ky, ix = hx - 1;
            uint4 val = {0u, 0u, 0u, 0u};
            if ((unsigned)iy < 128u && (unsigned)ix < 128u)
                val = *(const uint4*)(z1 + ((((n << 7) | iy) << 7 | ix) << 7) + (c << 5) + (icg << 3));
            int byt = (((ky * 132 + hx) << 6) + (icg << 4)) ^ ((hx & 14) << 3);
            *(uint4*)((char*)lz + byt) = val;
        }
        __syncthreads();
        uint4 braw[16];
        const uint4* wp = (const uint4*)(wB2 + ((((c << 4) * 4) + oct) * 64 + l) * 8);
        #pragma unroll
        for (int t = 0; t < 16; ++t) braw[t] = wp[t * 256];   // stride 4*64*8 shorts = 256 uint4
        #pragma unroll
        for (int s = 0; s < 2; ++s) {
            int oxbase = ((ph << 1) | s) << 4;
            #pragma unroll
            for (int ky = 0; ky < 4; ++ky) {
                #pragma unroll
                for (int kx = 0; kx < 4; ++kx) {
                    int hx = ((oxbase + col) << 1) + kx;
                    int byt = (((ky * 132 + hx) << 6) + (p << 4)) ^ ((hx & 14) << 3);
                    bf16x8 afrag = *(const bf16x8*)((const char*)lz + byt);
                    acc[s] = __builtin_amdgcn_mfma_f32_16x16x32_bf16(afrag,
                              __builtin_bit_cast(bf16x8, braw[(ky << 2) | kx]), acc[s], 0, 0, 0);
                }
            }
        }
    }
    int oc = (oct << 4) | col;
    float bl = bias[oc];
    #pragma unroll
    for (int s = 0; s < 2; ++s) {
        int oxbase = ((ph << 1) | s) << 4;
        #pragma unroll
        for (int r = 0; r < 4; ++r) {
            int ox = oxbase + (p << 2) + r;
            zq[(((((n << 6) | oy) << 6) | ox) << 6) + oc] = f2bf(acc[s][r] + bl);
        }
    }
}

// ---------------- codebook norms
__global__ __launch_bounds__(256) void cb_norms(const float* __restrict__ cb,
                                                float* __restrict__ cbn) {
    int k = blockIdx.x * 256 + threadIdx.x;    // 512
    const float* cp = cb + (k << 6);
    float s = 0.f;
    for (int d = 0; d < 64; ++d) s += cp[d] * cp[d];
    cbn[k] = s;
}

// ---------------- VQ via MFMA: scores = z @ cb^T - 0.5|c|^2; argmax; loss; q in place
__global__ __launch_bounds__(256) void vq_mfma(ushort* __restrict__ zq,
        const float* __restrict__ cb, const float* __restrict__ cbn,
        const ushort* __restrict__ cbB, float* __restrict__ accum) {
    __shared__ int sidx[256];
    int bid = blockIdx.x;                       // 512
    int tid = threadIdx.x;
    int w = tid >> 6, l = tid & 63;
    int rowbase = (bid << 8) + (w << 6);        // wave's 64 rows
    bf16x8 a0[4], a1[4];
    const ushort* zb = zq + ((size_t)rowbase << 6);
    #pragma unroll
    for (int s = 0; s < 4; ++s) {
        int r = (s << 4) | (l & 15);
        a0[s] = *(const bf16x8*)(zb + (r << 6) + ((l >> 4) << 3));
        a1[s] = *(const bf16x8*)(zb + (r << 6) + 32 + ((l >> 4) << 3));
    }
    float best[4][4];
    int bidx[4][4];
    #pragma unroll
    for (int s = 0; s < 4; ++s)
        for (int r = 0; r < 4; ++r) { best[s][r] = -1e30f; bidx[s][r] = 0; }
    for (int t = 0; t < 32; ++t) {
        int code = (t << 4) | (l & 15);
        float init = -0.5f * cbn[code];
        uint4 b0r = *(const uint4*)(cbB + (t << 10) + (l << 3));
        uint4 b1r = *(const uint4*)(cbB + (t << 10) + 512 + (l << 3));
        bf16x8 b0 = __builtin_bit_cast(bf16x8, b0r);
        bf16x8 b1 = __builtin_bit_cast(bf16x8, b1r);
        #pragma unroll
        for (int s = 0; s < 4; ++s) {
            f32x4 acc;
            acc[0] = init; acc[1] = init; acc[2] = init; acc[3] = init;
            acc = __builtin_amdgcn_mfma_f32_16x16x32_bf16(a0[s], b0, acc, 0, 0, 0);
            acc = __builtin_amdgcn_mfma_f32_16x16x32_bf16(a1[s], b1, acc, 0, 0, 0);
            #pragma unroll
            for (int r = 0; r < 4; ++r) {
                if (acc[r] > best[s][r]) { best[s][r] = acc[r]; bidx[s][r] = code; }
            }
        }
    }
    #pragma unroll
    for (int m = 1; m < 16; m <<= 1) {
        #pragma unroll
        for (int s = 0; s < 4; ++s)
            #pragma unroll
            for (int r = 0; r < 4; ++r) {
                float ob = __shfl_xor(best[s][r], m, 64);
                int oi = __shfl_xor(bidx[s][r], m, 64);
                if (ob > best[s][r] || (ob == best[s][r] && oi < bidx[s][r])) {
                    best[s][r] = ob; bidx[s][r] = oi;
                }
            }
    }
    if ((l & 15) == 0) {
        #pragma unroll
        for (int s = 0; s < 4; ++s)
            #pragma unroll
            for (int r = 0; r < 4; ++r)
                sidx[(w << 6) | (s << 4) | ((l >> 4) << 2) | r] = bidx[s][r];
    }
    __syncthreads();
    float lpart = 0.f;
    for (int u = tid; u < 1024; u += 256) {
        int row = u >> 2, qt = u & 3;
        int idx = sidx[row];
        size_t zoff = (((size_t)(bid << 8) + row) << 6) + (qt << 4);
        const float4* cp = (const float4*)(cb + (idx << 6) + (qt << 4));
        uint4* zp = (uint4*)(zq + zoff);
        uint4 u0 = zp[0], u1 = zp[1];
        float4 c0 = cp[0], c1 = cp[1], c2 = cp[2], c3 = cp[3];
        float d;
        d = c0.x - bflo(u0.x); lpart += d * d;
        d = c0.y - bfhi(u0.x); lpart += d * d;
        d = c0.z - bflo(u0.y); lpart += d * d;
        d = c0.w - bfhi(u0.y); lpart += d * d;
        d = c1.x - bflo(u0.z); lpart += d * d;
        d = c1.y - bfhi(u0.z); lpart += d * d;
        d = c1.z - bflo(u0.w); lpart += d * d;
        d = c1.w - bfhi(u0.w); lpart += d * d;
        d = c2.x - bflo(u1.x); lpart += d * d;
        d = c2.y - bfhi(u1.x); lpart += d * d;
        d = c2.z - bflo(u1.y); lpart += d * d;
        d = c2.w - bfhi(u1.y); lpart += d * d;
        d = c3.x - bflo(u1.z); lpart += d * d;
        d = c3.y - bfhi(u1.z); lpart += d * d;
        d = c3.z - bflo(u1.w); lpart += d * d;
        d = c3.w - bfhi(u1.w); lpart += d * d;
        uint4 o0, o1;
        o0.x = (unsigned)f2bf(c0.x) | ((unsigned)f2bf(c0.y) << 16);
        o0.y = (unsigned)f2bf(c0.z) | ((unsigned)f2bf(c0.w) << 16);
        o0.z = (unsigned)f2bf(c1.x) | ((unsigned)f2bf(c1.y) << 16);
        o0.w = (unsigned)f2bf(c1.z) | ((unsigned)f2bf(c1.w) << 16);
        o1.x = (unsigned)f2bf(c2.x) | ((unsigned)f2bf(c2.y) << 16);
        o1.y = (unsigned)f2bf(c2.z) | ((unsigned)f2bf(c2.w) << 16);
        o1.z = (unsigned)f2bf(c3.x) | ((unsigned)f2bf(c3.y) << 16);
        o1.w = (unsigned)f2bf(c3.z) | ((unsigned)f2bf(c3.w) << 16);
        zp[0] = o0; zp[1] = o1;
    }
    for (int off = 32; off; off >>= 1) lpart += __shfl_down(lpart, off);
    if ((tid & 63) == 0) atomicAdd(accum, lpart);
}

// ---------------- deconv1 via MFMA: q bf16 NHWC (32,64,64,64) -> h bf16 NHWC (32,128,128,128)
__global__ __launch_bounds__(512) void deconv1_mfma(const ushort* __restrict__ q,
        const ushort* __restrict__ wB, const float* __restrict__ bias,
        ushort* __restrict__ h) {
    __shared__ __align__(16) ushort lq[12672];   // 3 slots x 66 hx x 64 ic, byte^((hx&7)<<4)
    int bid = blockIdx.x;
    int a = bid & 63, n = bid >> 6;
    int tid = threadIdx.x;
    for (int c = tid; c < 1584; c += 512) {
        int slot = c / 528;
        int rem  = c - slot * 528;
        int hx   = rem >> 3;
        int icg  = rem & 7;
        uint4 val = {0u, 0u, 0u, 0u};
        int iy = a + slot - 1;
        int ix = hx - 1;
        if (hx >= 1 && hx <= 64 && (unsigned)iy < 64u)
            val = *(const uint4*)(q + ((((n << 6) | iy) << 6 | ix) << 6) + (icg << 3));
        int byt = ((((slot * 66 + hx) << 7) + (icg << 4))) ^ ((hx & 7) << 4);
        *(uint4*)((char*)lq + byt) = val;
    }
    __syncthreads();
    int l = tid & 63;
    int oct = tid >> 6;
    int col = l & 15, p = l >> 4;
    int oc = (oct << 4) | col;
    float bl = bias[oc];
    int oybase = a << 1;
    for (int cls = 0; cls < 4; ++cls) {
        int ry = cls >> 1, rx = cls & 1;
        f32x4 acc[4];
        #pragma unroll
        for (int s = 0; s < 4; ++s) { acc[s][0]=0.f; acc[s][1]=0.f; acc[s][2]=0.f; acc[s][3]=0.f; }
        #pragma unroll
        for (int kt = 0; kt < 8; ++kt) {
            uint4 braw = *(const uint4*)(wB + (((cls << 6) | (oct << 3) | kt) << 9) + (l << 3));
            bf16x8 bfrag = __builtin_bit_cast(bf16x8, braw);
            int dy = kt >> 2, dx = (kt >> 1) & 1;
            int ic0 = (kt & 1) << 5;
            int slot = 1 + ry - dy;
            #pragma unroll
            for (int sub = 0; sub < 4; ++sub) {
                int b = (sub << 4) | col;
                int hx = b + rx - dx + 1;
                int byt = ((((slot * 66 + hx) << 7) + (ic0 << 1) + (p << 4))) ^ ((hx & 7) << 4);
                bf16x8 afrag = *(const bf16x8*)((const char*)lq + byt);
                acc[sub] = __builtin_amdgcn_mfma_f32_16x16x32_bf16(afrag, bfrag, acc[sub], 0, 0, 0);
            }
        }
        int oy = oybase | ry;
        #pragma unroll
        for (int sub = 0; sub < 4; ++sub) {
            #pragma unroll
            for (int r = 0; r < 4; ++r) {
                int b = (sub << 4) + (p << 2) + r;
                int ox = (b << 1) | rx;
                float v = fmaxf(acc[sub][r] + bl, 0.f);
                h[(((((n << 7) | oy) << 7) | ox) << 7) | oc] = f2bf(v);
            }
        }
    }
}

// ---------------- deconv2: h bf16 NHWC -> recon (32,3,256,256), tanh; + loss finalize
__global__ __launch_bounds__(256) void deconv2_tanh(const ushort* __restrict__ h,
        const float* __restrict__ w,   // (ic=128, oc=3, 4, 4)
        const float* __restrict__ bias, const float* __restrict__ acc,
        float* __restrict__ out) {
    __shared__ float lw[48 * 129];             // [tap*3+oc][ic], odd stride kills bank conflicts
    int tid = threadIdx.x;
    for (int i = tid; i < 6144; i += 256) {
        int ic = i & 127;
        int r = i >> 7;                        // 0..47
        int oc = r % 3, tap = r / 3;
        lw[r * 129 + ic] = w[(ic * 3 + oc) * 16 + tap];
    }
    __syncthreads();
    int gid = blockIdx.x * 256 + tid;          // 2097152 = 32n*256oy*256ox
    int ox = gid & 255;
    int oy = (gid >> 8) & 255;
    int n = gid >> 16;
    float a0 = bias[0], a1 = bias[1], a2 = bias[2];
    int py = (oy + 1) & 1, px = (ox + 1) & 1;
    for (int dy = 0; dy < 2; ++dy) {
        int ky = py + 2 * dy;
        int iy = (oy + 1 - ky) >> 1;
        for (int dx = 0; dx < 2; ++dx) {
            int kx = px + 2 * dx;
            int ix = (ox + 1 - kx) >> 1;
            if ((unsigned)iy > 127u || (unsigned)ix > 127u) continue;
            const uint4* hp = (const uint4*)(h + ((((n << 7) | iy) << 7 | ix) << 7));
            const float* wr = lw + ((ky * 4 + kx) * 3) * 129;
            for (int c8 = 0; c8 < 16; ++c8) {
                uint4 u = hp[c8];
                float f0 = bflo(u.x), f1 = bfhi(u.x), f2 = bflo(u.y), f3 = bfhi(u.y);
                float f4 = bflo(u.z), f5 = bfhi(u.z), f6 = bflo(u.w), f7 = bfhi(u.w);
                const float* w0 = wr + c8 * 8;
                a0 += f0*w0[0] + f1*w0[1] + f2*w0[2] + f3*w0[3] + f4*w0[4] + f5*w0[5] + f6*w0[6] + f7*w0[7];
                const float* w1 = w0 + 129;
                a1 += f0*w1[0] + f1*w1[1] + f2*w1[2] + f3*w1[3] + f4*w1[4] + f5*w1[5] + f6*w1[6] + f7*w1[7];
                const float* w2 = w0 + 258;
                a2 += f0*w2[0] + f1*w2[1] + f2*w2[2] + f3*w2[3] + f4*w2[4] + f5*w2[5] + f6*w2[6] + f7*w2[7];
            }
        }
    }
    int ob = (n * 3 << 16) + (oy << 8) + ox;
    out[ob]           = tanhf(a0);
    out[ob + 65536]   = tanhf(a1);
    out[ob + 131072]  = tanhf(a2);
    if (gid == 0) out[6291456] = 1.25f * acc[0] / 8388608.0f;
}

extern "C" void kernel_launch(void* const* d_in, const int* in_sizes, int n_in,
                              void* d_out, int out_size, void* d_ws, size_t ws_size,
                              hipStream_t stream) {
    const float* x      = (const float*)d_in[0];
    const float* enc_w1 = (const float*)d_in[1];
    const float* enc_b1 = (const float*)d_in[2];
    const float* enc_w2 = (const float*)d_in[3];
    const float* enc_b2 = (const float*)d_in[4];
    const float* cb     = (const float*)d_in[5];
    const float* dec_w1 = (const float*)d_in[6];
    const float* dec_b1 = (const float*)d_in[7];
    const float* dec_w2 = (const float*)d_in[8];
    const float* dec_b2 = (const float*)d_in[9];
    float* out = (float*)d_out;

    // workspace layout (bytes): total ~151.6 MB (151.8 proven safe in R5)
    char* base = (char*)d_ws;
    ushort* z1h  = (ushort*)base;                   // 134217728 B: z1 bf16 NHWC, reused as h bf16 NHWC
    ushort* zq   = (ushort*)(base + 134217728);     //  16777216 B: z2 bf16 NHWC -> q bf16 in place
    ushort* wB2  = (ushort*)(base + 150994944);     //    262144 B: conv2 MFMA weights
    ushort* wB   = (ushort*)(base + 151257088);     //    262144 B: deconv1 MFMA weights
    ushort* wB1  = (ushort*)(base + 151519232);     //     16384 B: conv1 MFMA weights
    ushort* cbB  = (ushort*)(base + 151535616);     //     65536 B: codebook MFMA-B fragments
    float*  cbn  = (float*)(base + 151601152);      //      2048 B
    float*  acc  = (float*)(base + 151603200);      //         4 B

    hipMemsetAsync(acc, 0, 4, stream);
    repack_wb1<<<32, 256, 0, stream>>>(enc_w1, wB1);
    repack_w2<<<512, 256, 0, stream>>>(enc_w2, wB2);
    repack_wdec1<<<512, 256, 0, stream>>>(dec_w1, wB);
    repack_cb<<<128, 256, 0, stream>>>(cb, cbB);
    cb_norms<<<2, 256, 0, stream>>>(cb, cbn);
    conv1_mfma<<<4096, 512, 0, stream>>>(x, wB1, enc_b1, z1h);
    conv2_mfma<<<2048, 512, 0, stream>>>(z1h, wB2, enc_b2, zq);
    vq_mfma<<<512, 256, 0, stream>>>(zq, cb, cbn, cbB, acc);
    deconv1_mfma<<<2048, 512, 0, stream>>>(zq, wB, dec_b1, z1h);
    deconv2_tanh<<<8192, 256, 0, stream>>>(z1h, dec_w2, dec_b2, acc, out);
}